// Round 13
// baseline (153.617 us; speedup 1.0000x reference)
//
#include <hip/hip_runtime.h>
#include <math.h>

// Problem constants (fixed instance)
namespace {
constexpr int R_ = 32768;     // BS*N rows
constexpr int N_ = 16;
constexpr int NA_ = 30;
constexpr int BSB_ = R_ / N_; // 2048 batches
constexpr int NBLK_ = R_ / 32; // 1024 row-blocks (32 rows each)
}

typedef __bf16 bf16x8 __attribute__((ext_vector_type(8)));
typedef float f32x4 __attribute__((ext_vector_type(4)));

__device__ inline unsigned int f2bf(float f) {
    unsigned int u = __float_as_uint(f);
    return (u + 0x7fffu + ((u >> 16) & 1u)) >> 16;  // RTN-even
}
__device__ inline float bf2f(unsigned int us) {
    return __uint_as_float(us << 16);
}
__device__ inline unsigned int pack2(float a, float b) {
    return f2bf(a) | (f2bf(b) << 16);
}
__device__ inline uint4 pack8(float4 f0, float4 f1) {
    uint4 u;
    u.x = pack2(f0.x, f0.y); u.y = pack2(f0.z, f0.w);
    u.z = pack2(f1.x, f1.y); u.w = pack2(f1.z, f1.w);
    return u;
}
// Fast transcendentals (v_exp/v_rcp); rel err ~2^-21 << bf16 rounding 2^-9.
__device__ inline float fsig(float x)  { return __builtin_amdgcn_rcpf(1.f + __expf(-x)); }
__device__ inline float ftanh(float x) { return 1.f - 2.f * __builtin_amdgcn_rcpf(__expf(2.f * x) + 1.f); }

// A fragment from swizzled LDS tile (KC = 16B-chunks per row)
__device__ __forceinline__ bf16x8 lda_frag(const uint4* At, int KC, int row, int c) {
    return __builtin_bit_cast(bf16x8, At[(row * KC + c) ^ (row & 7)]);
}
// B fragment direct from global bf16 weights
__device__ __forceinline__ bf16x8 ldb_frag(const unsigned short* W, int row, int rstride, int c) {
    return __builtin_bit_cast(bf16x8, *(const uint4*)(W + (size_t)row * rstride + (size_t)c * 8));
}

// ---------------------------------------------------------------------------
// One-shot weight conversion f32 -> bf16 into workspace (concatenated).
namespace woff {
constexpr unsigned fc1 = 0;
constexpr unsigned ih  = 16384;
constexpr unsigned hh  = 65536;
constexpr unsigned l1  = 114688;
constexpr unsigned l2  = 122880;
constexpr unsigned m1  = 139264;
constexpr unsigned m2  = 204800;
constexpr unsigned kw  = 237568;
constexpr unsigned qw  = 241664;
constexpr unsigned v1  = 243712;
constexpr unsigned v2  = 292864;
constexpr unsigned f2  = 309248;
constexpr unsigned total = 347648;
}

__global__ __launch_bounds__(256)
void wcvt_kernel(const float* __restrict__ fc1_w, const float* __restrict__ w_ih,
                 const float* __restrict__ w_hh, const float* __restrict__ lse_w1,
                 const float* __restrict__ lse_w2, const float* __restrict__ me_w1,
                 const float* __restrict__ me_w2, const float* __restrict__ k_w,
                 const float* __restrict__ q_w, const float* __restrict__ v_w1,
                 const float* __restrict__ v_w2, const float* __restrict__ fc2_w,
                 unsigned short* __restrict__ dst)
{
    unsigned i = blockIdx.x * 256 + threadIdx.x;
    if (i >= woff::total) return;
    const float* src; unsigned base;
    if      (i < woff::ih) { src = fc1_w;  base = woff::fc1; }
    else if (i < woff::hh) { src = w_ih;   base = woff::ih; }
    else if (i < woff::l1) { src = w_hh;   base = woff::hh; }
    else if (i < woff::l2) { src = lse_w1; base = woff::l1; }
    else if (i < woff::m1) { src = lse_w2; base = woff::l2; }
    else if (i < woff::m2) { src = me_w1;  base = woff::m1; }
    else if (i < woff::kw) { src = me_w2;  base = woff::m2; }
    else if (i < woff::qw) { src = k_w;    base = woff::kw; }
    else if (i < woff::v1) { src = q_w;    base = woff::qw; }
    else if (i < woff::v2) { src = v_w1;   base = woff::v1; }
    else if (i < woff::f2) { src = v_w2;   base = woff::v2; }
    else                   { src = fc2_w;  base = woff::f2; }
    dst[i] = (unsigned short)f2bf(src[i - base]);
}

// ---------------------------------------------------------------------------
// K1 "front": fc1 -> GRU -> lse1 -> lse2 -> me1 (+BN partials + hl), 32-row
// blocks. x, lt, le live only in LDS. Writes: hb, t1, psum/psq, hl.
__global__ __launch_bounds__(256, 4)
void front(const float* __restrict__ inputs, const float* __restrict__ hidden,
           const float* __restrict__ latent,
           const unsigned short* __restrict__ fc1w, const float* __restrict__ fc1_b,
           const unsigned short* __restrict__ wih, const unsigned short* __restrict__ whh,
           const float* __restrict__ b_ih, const float* __restrict__ b_hh,
           const unsigned short* __restrict__ l1w, const float* __restrict__ b1,
           const unsigned short* __restrict__ l2w, const float* __restrict__ b2,
           const unsigned short* __restrict__ m1w, const float* __restrict__ me_b1,
           const unsigned short* __restrict__ f2w, const float* __restrict__ fc2_b,
           unsigned short* __restrict__ hb, unsigned short* __restrict__ t1,
           float* __restrict__ psum, float* __restrict__ psq,
           float* __restrict__ hl)
{
    __shared__ uint4 buf1[32 * 32];  // [x | hidden] -> lt(0..15) -> T1 bounce
    __shared__ uint4 buf2[32 * 32];  // inputs(0..15)+latent(16..23) -> [h | le]
    const int tid = threadIdx.x;
    const int r0 = blockIdx.x * 32;
    const int lane = tid & 63, w = tid >> 6;
    const int m = lane & 15, g = lane >> 4;

    // ---- stage inputs -> buf2(0..15), hidden -> buf1(16..31), latent -> buf2(16..23)
    for (int idx = tid; idx < 32 * 16; idx += 256) {
        int row = idx >> 4, c = idx & 15;
        const float4* p = (const float4*)(inputs + (size_t)(r0 + row) * 128 + c * 8);
        buf2[(row * 32 + c) ^ (row & 7)] = pack8(p[0], p[1]);
        const float4* ph = (const float4*)(hidden + (size_t)(r0 + row) * 128 + c * 8);
        buf1[(row * 32 + (16 + c)) ^ (row & 7)] = pack8(ph[0], ph[1]);
    }
    for (int idx = tid; idx < 32 * 8; idx += 256) {
        int row = idx >> 3, c = idx & 7;
        const float4* p = (const float4*)(latent + (size_t)(r0 + row) * 64 + c * 8);
        buf2[(row * 32 + (16 + c)) ^ (row & 7)] = pack8(p[0], p[1]);
    }
    __syncthreads();

    // ---- fc1: x = relu(inputs@fc1^T+b) -> buf1 chunks 0..15; wave w: cols w*32
    {
        f32x4 acc[2][2] = {};
        #pragma unroll
        for (int ks = 0; ks < 4; ++ks) {
            bf16x8 af[2], bf[2];
            #pragma unroll
            for (int fr = 0; fr < 2; ++fr)
                af[fr] = lda_frag(buf2, 32, fr * 16 + m, ks * 4 + g);
            #pragma unroll
            for (int fc = 0; fc < 2; ++fc)
                bf[fc] = ldb_frag(fc1w, w * 32 + fc * 16 + m, 128, ks * 4 + g);
            #pragma unroll
            for (int fr = 0; fr < 2; ++fr)
                #pragma unroll
                for (int fc = 0; fc < 2; ++fc)
                    acc[fr][fc] = __builtin_amdgcn_mfma_f32_16x16x32_bf16(
                        af[fr], bf[fc], acc[fr][fc], 0, 0, 0);
        }
        #pragma unroll
        for (int fc = 0; fc < 2; ++fc) {
            int col = w * 32 + fc * 16 + m;
            float bv = fc1_b[col];
            int c = col >> 3, el = col & 7;
            #pragma unroll
            for (int fr = 0; fr < 2; ++fr) {
                #pragma unroll
                for (int i = 0; i < 4; ++i) {
                    int row = fr * 16 + g * 4 + i;
                    float v = acc[fr][fc][i] + bv;
                    v = v > 0.f ? v : 0.f;
                    ((unsigned short*)buf1)[((row * 32 + c) ^ (row & 7)) * 8 + el] =
                        (unsigned short)f2bf(v);
                }
            }
        }
    }
    __syncthreads();

    // ---- GRU over A=buf1 [x|hidden]; h -> buf2 chunks 0..15 (inputs dead)
    {
        f32x4 rr[2][2] = {}, zz[2][2] = {}, ni[2][2] = {}, nh[2][2] = {};
        #pragma unroll
        for (int ks = 0; ks < 4; ++ks) {  // x part: wih
            bf16x8 af[2], brr[2], bzz[2], bnn[2];
            #pragma unroll
            for (int fr = 0; fr < 2; ++fr)
                af[fr] = lda_frag(buf1, 32, fr * 16 + m, ks * 4 + g);
            #pragma unroll
            for (int fc = 0; fc < 2; ++fc) {
                int ro = w * 32 + fc * 16 + m;
                brr[fc] = ldb_frag(wih, ro, 128, ks * 4 + g);
                bzz[fc] = ldb_frag(wih, 128 + ro, 128, ks * 4 + g);
                bnn[fc] = ldb_frag(wih, 256 + ro, 128, ks * 4 + g);
            }
            #pragma unroll
            for (int fr = 0; fr < 2; ++fr)
                #pragma unroll
                for (int fc = 0; fc < 2; ++fc) {
                    rr[fr][fc] = __builtin_amdgcn_mfma_f32_16x16x32_bf16(af[fr], brr[fc], rr[fr][fc], 0, 0, 0);
                    zz[fr][fc] = __builtin_amdgcn_mfma_f32_16x16x32_bf16(af[fr], bzz[fc], zz[fr][fc], 0, 0, 0);
                    ni[fr][fc] = __builtin_amdgcn_mfma_f32_16x16x32_bf16(af[fr], bnn[fc], ni[fr][fc], 0, 0, 0);
                }
        }
        #pragma unroll
        for (int ks = 0; ks < 4; ++ks) {  // hidden part: whh
            bf16x8 af[2], brr[2], bzz[2], bnn[2];
            #pragma unroll
            for (int fr = 0; fr < 2; ++fr)
                af[fr] = lda_frag(buf1, 32, fr * 16 + m, 16 + ks * 4 + g);
            #pragma unroll
            for (int fc = 0; fc < 2; ++fc) {
                int ro = w * 32 + fc * 16 + m;
                brr[fc] = ldb_frag(whh, ro, 128, ks * 4 + g);
                bzz[fc] = ldb_frag(whh, 128 + ro, 128, ks * 4 + g);
                bnn[fc] = ldb_frag(whh, 256 + ro, 128, ks * 4 + g);
            }
            #pragma unroll
            for (int fr = 0; fr < 2; ++fr)
                #pragma unroll
                for (int fc = 0; fc < 2; ++fc) {
                    rr[fr][fc] = __builtin_amdgcn_mfma_f32_16x16x32_bf16(af[fr], brr[fc], rr[fr][fc], 0, 0, 0);
                    zz[fr][fc] = __builtin_amdgcn_mfma_f32_16x16x32_bf16(af[fr], bzz[fc], zz[fr][fc], 0, 0, 0);
                    nh[fr][fc] = __builtin_amdgcn_mfma_f32_16x16x32_bf16(af[fr], bnn[fc], nh[fr][fc], 0, 0, 0);
                }
        }
        #pragma unroll
        for (int fc = 0; fc < 2; ++fc) {
            int c = w * 32 + fc * 16 + m;
            float brz = b_ih[c] + b_hh[c];
            float bzz2 = b_ih[128 + c] + b_hh[128 + c];
            float bin = b_ih[256 + c], bhn = b_hh[256 + c];
            int hc = 16 + (c >> 3), hel = c & 7;   // hidden chunk in buf1
            int oc = c >> 3, oel = c & 7;          // h chunk in buf2
            #pragma unroll
            for (int fr = 0; fr < 2; ++fr) {
                #pragma unroll
                for (int i = 0; i < 4; ++i) {
                    int row = fr * 16 + g * 4 + i;
                    float rv = fsig(rr[fr][fc][i] + brz);
                    float zv = fsig(zz[fr][fc][i] + bzz2);
                    float ng = ftanh(ni[fr][fc][i] + bin + rv * (nh[fr][fc][i] + bhn));
                    float hp = bf2f(((unsigned short*)buf1)[((row * 32 + hc) ^ (row & 7)) * 8 + hel]);
                    float hv = ng + zv * (hp - ng);
                    ((unsigned short*)buf2)[((row * 32 + oc) ^ (row & 7)) * 8 + oel] =
                        (unsigned short)f2bf(hv);
                }
            }
        }
    }
    __syncthreads();

    // ---- hb store (coalesced from swizzled buf2 h chunks)
    for (int idx = tid; idx < 32 * 16; idx += 256) {
        int row = idx >> 4, c = idx & 15;
        *(uint4*)(hb + (size_t)(r0 + row) * 128 + c * 8) = buf2[(row * 32 + c) ^ (row & 7)];
    }

    // ---- lse1: lt = relu(latent@l1^T) -> buf1 chunks 0..15 (x dead)
    {
        f32x4 acc[2][2] = {};
        #pragma unroll
        for (int ks = 0; ks < 2; ++ks) {
            bf16x8 af[2], bf[2];
            #pragma unroll
            for (int fr = 0; fr < 2; ++fr)
                af[fr] = lda_frag(buf2, 32, fr * 16 + m, 16 + ks * 4 + g);
            #pragma unroll
            for (int fc = 0; fc < 2; ++fc)
                bf[fc] = ldb_frag(l1w, w * 32 + fc * 16 + m, 64, ks * 4 + g);
            #pragma unroll
            for (int fr = 0; fr < 2; ++fr)
                #pragma unroll
                for (int fc = 0; fc < 2; ++fc)
                    acc[fr][fc] = __builtin_amdgcn_mfma_f32_16x16x32_bf16(
                        af[fr], bf[fc], acc[fr][fc], 0, 0, 0);
        }
        #pragma unroll
        for (int fc = 0; fc < 2; ++fc) {
            int col = w * 32 + fc * 16 + m;
            float bv = b1[col];
            int c = col >> 3, el = col & 7;
            #pragma unroll
            for (int fr = 0; fr < 2; ++fr) {
                #pragma unroll
                for (int i = 0; i < 4; ++i) {
                    int row = fr * 16 + g * 4 + i;
                    float v = acc[fr][fc][i] + bv;
                    v = v > 0.f ? v : 0.f;
                    ((unsigned short*)buf1)[((row * 32 + c) ^ (row & 7)) * 8 + el] =
                        (unsigned short)f2bf(v);
                }
            }
        }
    }
    __syncthreads();

    // ---- lse2: le = lt@l2^T -> buf2 chunks 16..31 (latent dead)
    {
        f32x4 acc[2][2] = {};
        #pragma unroll
        for (int ks = 0; ks < 4; ++ks) {
            bf16x8 af[2], bf[2];
            #pragma unroll
            for (int fr = 0; fr < 2; ++fr)
                af[fr] = lda_frag(buf1, 32, fr * 16 + m, ks * 4 + g);
            #pragma unroll
            for (int fc = 0; fc < 2; ++fc)
                bf[fc] = ldb_frag(l2w, w * 32 + fc * 16 + m, 128, ks * 4 + g);
            #pragma unroll
            for (int fr = 0; fr < 2; ++fr)
                #pragma unroll
                for (int fc = 0; fc < 2; ++fc)
                    acc[fr][fc] = __builtin_amdgcn_mfma_f32_16x16x32_bf16(
                        af[fr], bf[fc], acc[fr][fc], 0, 0, 0);
        }
        #pragma unroll
        for (int fc = 0; fc < 2; ++fc) {
            int col = w * 32 + fc * 16 + m;
            float bv = b2[col];
            int c = 16 + (col >> 3), el = col & 7;
            #pragma unroll
            for (int fr = 0; fr < 2; ++fr) {
                #pragma unroll
                for (int i = 0; i < 4; ++i) {
                    int row = fr * 16 + g * 4 + i;
                    float v = acc[fr][fc][i] + bv;
                    ((unsigned short*)buf2)[((row * 32 + c) ^ (row & 7)) * 8 + el] =
                        (unsigned short)f2bf(v);
                }
            }
        }
    }
    __syncthreads();

    // ---- me1: t1 = [h|le]@m1^T + b (K=256, O=256) + BN partials; T1 -> buf1
    unsigned short* t1s = (unsigned short*)buf1;
    for (int ot = 0; ot < 2; ++ot) {
        const int o0 = ot * 128 + w * 32;
        f32x4 acc[2][2] = {};
        #pragma unroll
        for (int ks = 0; ks < 8; ++ks) {
            bf16x8 af[2], bf[2];
            #pragma unroll
            for (int fr = 0; fr < 2; ++fr)
                af[fr] = lda_frag(buf2, 32, fr * 16 + m, ks * 4 + g);
            #pragma unroll
            for (int fc = 0; fc < 2; ++fc)
                bf[fc] = ldb_frag(m1w, o0 + fc * 16 + m, 256, ks * 4 + g);
            #pragma unroll
            for (int fr = 0; fr < 2; ++fr)
                #pragma unroll
                for (int fc = 0; fc < 2; ++fc)
                    acc[fr][fc] = __builtin_amdgcn_mfma_f32_16x16x32_bf16(
                        af[fr], bf[fc], acc[fr][fc], 0, 0, 0);
        }
        #pragma unroll
        for (int fc = 0; fc < 2; ++fc) {
            int col = o0 + fc * 16 + m;
            float bv = me_b1[col];
            float s = 0.f, q = 0.f;
            #pragma unroll
            for (int fr = 0; fr < 2; ++fr) {
                #pragma unroll
                for (int i = 0; i < 4; ++i) {
                    int rowl = fr * 16 + g * 4 + i;
                    float v = acc[fr][fc][i] + bv;
                    t1s[rowl * 256 + col] = (unsigned short)f2bf(v);
                    s += v; q += v * v;
                }
            }
            s += __shfl_xor(s, 16); s += __shfl_xor(s, 32);  // over g (all 32 rows)
            q += __shfl_xor(q, 16); q += __shfl_xor(q, 32);
            if (lane < 16) {
                psum[(size_t)blockIdx.x * 256 + col] = s;
                psq[(size_t)blockIdx.x * 256 + col] = q;
            }
        }
    }
    __syncthreads();
    for (int idx = tid; idx < 32 * 32; idx += 256) {  // coalesced t1 store
        int row = idx >> 5, c = idx & 31;
        *(uint4*)(t1 + (size_t)(r0 + row) * 256 + c * 8) = buf1[row * 32 + c];
    }

    // ---- fused hl: waves 0-1 rows w*16..w*16+15, cols 0..29
    if (w < 2) {
        f32x4 acc[2] = {};
        #pragma unroll
        for (int ks = 0; ks < 8; ++ks) {
            bf16x8 af = lda_frag(buf2, 32, w * 16 + m, ks * 4 + g);
            bf16x8 bf[2];
            #pragma unroll
            for (int fc = 0; fc < 2; ++fc) {
                int col = fc * 16 + m;
                bf[fc] = (col < NA_) ? ldb_frag(f2w, col, 1280, ks * 4 + g) : bf16x8{};
            }
            #pragma unroll
            for (int fc = 0; fc < 2; ++fc)
                acc[fc] = __builtin_amdgcn_mfma_f32_16x16x32_bf16(af, bf[fc], acc[fc], 0, 0, 0);
        }
        #pragma unroll
        for (int fc = 0; fc < 2; ++fc) {
            int col = fc * 16 + m;
            if (col < NA_) {
                float bv = fc2_b[col];
                #pragma unroll
                for (int i = 0; i < 4; ++i) {
                    int row = r0 + w * 16 + g * 4 + i;
                    hl[(size_t)row * NA_ + col] = acc[fc][i] + bv;
                }
            }
        }
    }
}

// ---------------------------------------------------------------------------
// Parallel BN finalize: one block per feature; threads stride over NBLK_.
__global__ __launch_bounds__(256)
void bn_final_kernel(const float* __restrict__ psum, const float* __restrict__ psq,
                     const float* __restrict__ g, const float* __restrict__ beta,
                     float* __restrict__ scale, float* __restrict__ shift)
{
    __shared__ float redS[4], redQ[4];
    const int f = blockIdx.x;
    const int tid = threadIdx.x;
    float s = 0.f, q = 0.f;
    for (int b = tid; b < NBLK_; b += 256) {
        s += psum[(size_t)b * 256 + f];
        q += psq[(size_t)b * 256 + f];
    }
    #pragma unroll
    for (int off = 32; off >= 1; off >>= 1) {
        s += __shfl_down(s, off);
        q += __shfl_down(q, off);
    }
    if ((tid & 63) == 0) { redS[tid >> 6] = s; redQ[tid >> 6] = q; }
    __syncthreads();
    if (tid == 0) {
        s = redS[0] + redS[1] + redS[2] + redS[3];
        q = redQ[0] + redQ[1] + redQ[2] + redQ[3];
        float mean = s / (float)R_;
        float var = q / (float)R_ - mean * mean;
        float istd = rsqrtf(var + 1e-5f);
        float sc = g[f] * istd;
        scale[f] = sc;
        shift[f] = beta[f] - mean * sc;
    }
}

// ---------------------------------------------------------------------------
// K2 "back": me2(BN(t1)) -> pm [LDS] -> kq-norm [LDS] -> v1 -> v2 -> value
// [LDS] -> vproj [LDS] -> softmax+combine -> out. Writes only `out`.
__global__ __launch_bounds__(256, 4)
void back(const unsigned short* __restrict__ t1,
          const float* __restrict__ scale, const float* __restrict__ shift,
          const unsigned short* __restrict__ W2, const float* __restrict__ me2_b,
          const float* __restrict__ eps,
          const unsigned short* __restrict__ hb,
          const unsigned short* __restrict__ kwb, const float* __restrict__ k_b,
          const unsigned short* __restrict__ qwb, const float* __restrict__ q_b,
          const unsigned short* __restrict__ v1w, const float* __restrict__ v1_b,
          const unsigned short* __restrict__ v2w, const float* __restrict__ v2_b,
          const float* __restrict__ w2f, const float* __restrict__ hl,
          float* __restrict__ outv)
{
    __shared__ uint4 bufA[32 * 32];   // 16 KB: t1(BN) -> t3 -> float scratch (vp, al)
    __shared__ uint4 bufB[32 * 24];   // 12 KB: [h 0..15 | pm 16..23] -> value bounce
    __shared__ float khs[32][33], qhs[32][33];
    __shared__ float sc_s[256], sh_s[256];
    const int tid = threadIdx.x;
    const int r0 = blockIdx.x * 32;
    const int lane = tid & 63, w = tid >> 6;
    const int m = lane & 15, g = lane >> 4;

    sc_s[tid] = scale[tid];
    sh_s[tid] = shift[tid];
    for (int idx = tid; idx < 32 * 16; idx += 256) {
        int row = idx >> 4, c = idx & 15;
        bufB[(row * 24 + c) ^ (row & 7)] =
            *(const uint4*)(hb + (size_t)(r0 + row) * 128 + c * 8);
    }
    __syncthreads();

    // ---- stage t1 with BN+lrelu -> bufA (swizzled)
    for (int idx = tid; idx < 32 * 32; idx += 256) {
        int row = idx >> 5, c = idx & 31;
        uint4 u = *(const uint4*)(t1 + (size_t)(r0 + row) * 256 + c * 8);
        unsigned int vv[4] = {u.x, u.y, u.z, u.w};
        float f[8];
        #pragma unroll
        for (int q2 = 0; q2 < 4; ++q2) {
            f[2 * q2]     = __uint_as_float((vv[q2] & 0xffffu) << 16);
            f[2 * q2 + 1] = __uint_as_float(vv[q2] & 0xffff0000u);
        }
        int k = c * 8;
        #pragma unroll
        for (int j = 0; j < 8; ++j) {
            float v = f[j] * sc_s[k + j] + sh_s[k + j];
            f[j] = v > 0.f ? v : 0.01f * v;
        }
        uint4 r;
        r.x = pack2(f[0], f[1]); r.y = pack2(f[2], f[3]);
        r.z = pack2(f[4], f[5]); r.w = pack2(f[6], f[7]);
        bufA[(row * 32 + c) ^ (row & 7)] = r;
    }
    __syncthreads();

    // ---- me2: wave w owns mean col w*16+m, std col 64+w*16+m; pm -> bufB 16..23
    {
        f32x4 acc[2][2] = {};
        #pragma unroll
        for (int ks = 0; ks < 8; ++ks) {
            bf16x8 af[2], bf[2];
            #pragma unroll
            for (int fr = 0; fr < 2; ++fr)
                af[fr] = lda_frag(bufA, 32, fr * 16 + m, ks * 4 + g);
            bf[0] = ldb_frag(W2, w * 16 + m, 256, ks * 4 + g);
            bf[1] = ldb_frag(W2, 64 + w * 16 + m, 256, ks * 4 + g);
            #pragma unroll
            for (int fr = 0; fr < 2; ++fr)
                #pragma unroll
                for (int fc = 0; fc < 2; ++fc)
                    acc[fr][fc] = __builtin_amdgcn_mfma_f32_16x16x32_bf16(
                        af[fr], bf[fc], acc[fr][fc], 0, 0, 0);
        }
        int cp = w * 16 + m;  // 0..63
        float bv0 = me2_b[cp], bv1 = me2_b[64 + cp];
        int hc = 16 + (cp >> 3), hel = cp & 7;
        #pragma unroll
        for (int fr = 0; fr < 2; ++fr) {
            #pragma unroll
            for (int i = 0; i < 4; ++i) {
                float vm = acc[fr][0][i] + bv0;
                vm = vm > 0.f ? vm : 0.01f * vm;
                vm = fminf(fmaxf(vm, -1.f), 1.f);
                float vs = acc[fr][1][i] + bv1;
                vs = vs > 0.f ? vs : 0.01f * vs;
                vs = fminf(fmaxf(vs, 0.5f), 1.f);
                int row = fr * 16 + g * 4 + i;
                float e = eps[(size_t)(r0 + row) * 64 + cp];
                ((unsigned short*)bufB)[((row * 24 + hc) ^ (row & 7)) * 8 + hel] =
                    (unsigned short)f2bf(vm + vs * e);
            }
        }
    }
    __syncthreads();   // pm visible; bufA (t1) dead after v1 writes begin below

    // ---- kq-norm: wave 0 -> khs, wave 1 -> qhs (LDS only)
    if (w < 2) {
        const bool isq = (w == 1);
        f32x4 acc[2][2] = {};
        const int nks = isq ? 2 : 4;
        for (int ks = 0; ks < nks; ++ks) {
            bf16x8 af[2], bf[2];
            #pragma unroll
            for (int fr = 0; fr < 2; ++fr)
                af[fr] = lda_frag(bufB, 24, fr * 16 + m, (isq ? 16 : 0) + ks * 4 + g);
            #pragma unroll
            for (int fc = 0; fc < 2; ++fc)
                bf[fc] = isq ? ldb_frag(qwb, fc * 16 + m, 64, ks * 4 + g)
                             : ldb_frag(kwb, fc * 16 + m, 128, ks * 4 + g);
            #pragma unroll
            for (int fr = 0; fr < 2; ++fr)
                #pragma unroll
                for (int fc = 0; fc < 2; ++fc)
                    acc[fr][fc] = __builtin_amdgcn_mfma_f32_16x16x32_bf16(
                        af[fr], bf[fc], acc[fr][fc], 0, 0, 0);
        }
        const float* bias = isq ? q_b : k_b;
        float b0 = bias[m], b1 = bias[16 + m];
        #pragma unroll
        for (int fr = 0; fr < 2; ++fr) {
            #pragma unroll
            for (int i = 0; i < 4; ++i) {
                float v0 = acc[fr][0][i] + b0;
                float v1 = acc[fr][1][i] + b1;
                float ss = v0 * v0 + v1 * v1;
                ss += __shfl_xor(ss, 1); ss += __shfl_xor(ss, 2);
                ss += __shfl_xor(ss, 4); ss += __shfl_xor(ss, 8);
                float inv = 1.f / fmaxf(sqrtf(ss), 1e-8f);
                int row = fr * 16 + g * 4 + i;
                if (isq) { qhs[row][m] = v0 * inv; qhs[row][16 + m] = v1 * inv; }
                else     { khs[row][m] = v0 * inv; khs[row][16 + m] = v1 * inv; }
            }
        }
    }

    // ---- v1: t3 = lrelu([h|pm]@v1^T) -> bufA
    for (int ot = 0; ot < 2; ++ot) {
        const int o0 = ot * 128 + w * 32;
        f32x4 acc[2][2] = {};
        #pragma unroll
        for (int ks = 0; ks < 6; ++ks) {
            bf16x8 af[2], bf[2];
            #pragma unroll
            for (int fr = 0; fr < 2; ++fr)
                af[fr] = lda_frag(bufB, 24, fr * 16 + m, ks * 4 + g);
            #pragma unroll
            for (int fc = 0; fc < 2; ++fc)
                bf[fc] = ldb_frag(v1w, o0 + fc * 16 + m, 192, ks * 4 + g);
            #pragma unroll
            for (int fr = 0; fr < 2; ++fr)
                #pragma unroll
                for (int fc = 0; fc < 2; ++fc)
                    acc[fr][fc] = __builtin_amdgcn_mfma_f32_16x16x32_bf16(
                        af[fr], bf[fc], acc[fr][fc], 0, 0, 0);
        }
        #pragma unroll
        for (int fc = 0; fc < 2; ++fc) {
            int col = o0 + fc * 16 + m;
            float bv = v1_b[col];
            int c = col >> 3, el = col & 7;
            #pragma unroll
            for (int fr = 0; fr < 2; ++fr) {
                #pragma unroll
                for (int i = 0; i < 4; ++i) {
                    int row = fr * 16 + g * 4 + i;
                    float v = acc[fr][fc][i] + bv;
                    v = v > 0.f ? v : 0.01f * v;
                    ((unsigned short*)bufA)[((row * 32 + c) ^ (row & 7)) * 8 + el] =
                        (unsigned short)f2bf(v);
                }
            }
        }
    }
    __syncthreads();

    // ---- v2: value = t3@v2^T -> bufB linear (32x64 bf16)
    {
        f32x4 acc[2] = {};
        #pragma unroll
        for (int ks = 0; ks < 8; ++ks) {
            bf16x8 af[2];
            #pragma unroll
            for (int fr = 0; fr < 2; ++fr)
                af[fr] = lda_frag(bufA, 32, fr * 16 + m, ks * 4 + g);
            bf16x8 bf = ldb_frag(v2w, w * 16 + m, 256, ks * 4 + g);
            #pragma unroll
            for (int fr = 0; fr < 2; ++fr)
                acc[fr] = __builtin_amdgcn_mfma_f32_16x16x32_bf16(af[fr], bf, acc[fr], 0, 0, 0);
        }
        int col = w * 16 + m;
        float bv = v2_b[col];
        unsigned short* vb = (unsigned short*)bufB;
        #pragma unroll
        for (int fr = 0; fr < 2; ++fr) {
            #pragma unroll
            for (int i = 0; i < 4; ++i) {
                int rowl = fr * 16 + g * 4 + i;
                vb[rowl * 64 + col] = (unsigned short)f2bf(acc[fr][i] + bv);
            }
        }
    }
    __syncthreads();  // value in bufB; bufA dead -> float scratch

    // ---- vproj: vp[row][na] = w2slice(row%16) . value[row] (f32, in bufA)
    float* vp = (float*)bufA;           // [32][32] stride 32
    float* al = vp + 32 * 32;           // [32][16]
    {
        const unsigned short* vb = (const unsigned short*)bufB;
        for (int task = tid; task < 32 * NA_; task += 256) {
            int row = task / NA_, na = task - row * NA_;
            int j = row & 15;
            const float* wp = w2f + (size_t)na * 1280 + 256 + j * 64;
            float acc = 0.f;
            #pragma unroll
            for (int k8 = 0; k8 < 8; ++k8) {
                uint4 uv = *(const uint4*)(vb + row * 64 + k8 * 8);
                float4 w0 = *(const float4*)(wp + k8 * 8);
                float4 w1 = *(const float4*)(wp + k8 * 8 + 4);
                acc += bf2f(uv.x & 0xffffu) * w0.x + bf2f(uv.x >> 16) * w0.y;
                acc += bf2f(uv.y & 0xffffu) * w0.z + bf2f(uv.y >> 16) * w0.w;
                acc += bf2f(uv.z & 0xffffu) * w1.x + bf2f(uv.z >> 16) * w1.y;
                acc += bf2f(uv.w & 0xffffu) * w1.z + bf2f(uv.w >> 16) * w1.w;
            }
            vp[row * 32 + na] = acc;
        }
    }
    __syncthreads();

    // ---- logits + softmax (2 batches: rows 0..15, 16..31)
    for (int base = 0; base < 512; base += 256) {
        int idx = base + tid;
        int rowi = idx >> 4;            // 0..31
        int j = idx & 15;
        int qrow = (rowi & 16) | j;     // same batch, agent j
        float l = 0.f;
        #pragma unroll
        for (int a = 0; a < 32; ++a) l = fmaf(khs[rowi][a], qhs[qrow][a], l);
        float mx = l;
        #pragma unroll
        for (int mm = 8; mm >= 1; mm >>= 1) mx = fmaxf(mx, __shfl_xor(mx, mm));
        float e = __expf(l - mx);
        float s = e;
        #pragma unroll
        for (int mm = 8; mm >= 1; mm >>= 1) s += __shfl_xor(s, mm);
        float a = e / s;
        if ((rowi & 15) == j) a = 0.f;
        al[rowi * 16 + j] = a;
    }
    __syncthreads();

    // ---- combine: out[row][na] = hl + sum_j al[row][j] * vp[batch*16+j][na]
    for (int task = tid; task < 32 * NA_; task += 256) {
        int rowi = task / NA_, na = task - rowi * NA_;
        int bb = rowi & 16;
        float acc = hl[(size_t)(r0 + rowi) * NA_ + na];
        #pragma unroll
        for (int j = 0; j < 16; ++j)
            acc = fmaf(al[rowi * 16 + j], vp[(bb + j) * 32 + na], acc);
        outv[(size_t)(r0 + rowi) * NA_ + na] = acc;
    }
}

extern "C" void kernel_launch(void* const* d_in, const int* in_sizes, int n_in,
                              void* d_out, int out_size, void* d_ws, size_t ws_size,
                              hipStream_t stream)
{
    (void)in_sizes; (void)n_in; (void)out_size; (void)ws_size;
    const float* inputs  = (const float*)d_in[0];
    const float* hidden  = (const float*)d_in[1];
    const float* latent  = (const float*)d_in[2];
    const float* eps     = (const float*)d_in[3];
    const float* fc1_w   = (const float*)d_in[4];
    const float* fc1_b   = (const float*)d_in[5];
    const float* w_ih    = (const float*)d_in[6];
    const float* w_hh    = (const float*)d_in[7];
    const float* b_ih    = (const float*)d_in[8];
    const float* b_hh    = (const float*)d_in[9];
    const float* lse_w1  = (const float*)d_in[10];
    const float* lse_b1  = (const float*)d_in[11];
    const float* lse_w2  = (const float*)d_in[12];
    const float* lse_b2  = (const float*)d_in[13];
    const float* me_w1   = (const float*)d_in[14];
    const float* me_b1   = (const float*)d_in[15];
    const float* me_g    = (const float*)d_in[16];
    const float* me_beta = (const float*)d_in[17];
    const float* me_w2   = (const float*)d_in[18];
    const float* me_b2   = (const float*)d_in[19];
    const float* k_w     = (const float*)d_in[20];
    const float* k_b     = (const float*)d_in[21];
    const float* q_w     = (const float*)d_in[22];
    const float* q_b     = (const float*)d_in[23];
    const float* v_w1    = (const float*)d_in[24];
    const float* v_b1    = (const float*)d_in[25];
    const float* v_w2    = (const float*)d_in[26];
    const float* v_b2    = (const float*)d_in[27];
    const float* fc2_w   = (const float*)d_in[28];
    const float* fc2_b   = (const float*)d_in[29];

    const size_t R = R_;
    unsigned short* bws = (unsigned short*)d_ws;
    unsigned short* hb   = bws;               // R*128
    unsigned short* t1b  = hb + R * 128;      // R*256
    unsigned short* wb   = t1b + R * 256;     // 347648 (bf16 weights)
    float* fws  = (float*)(wb + woff::total);
    float* hlf  = fws;                 // R*30
    float* psum = hlf + R * 30;        // NBLK_*256
    float* psq  = psum + (size_t)NBLK_ * 256;
    float* scale = psq + (size_t)NBLK_ * 256;
    float* shift = scale + 256;

    dim3 blk(256);
    dim3 g1024(NBLK_);

    // 0) weights -> bf16
    wcvt_kernel<<<dim3((woff::total + 255) / 256), blk, 0, stream>>>(
        fc1_w, w_ih, w_hh, lse_w1, lse_w2, me_w1, me_w2, k_w, q_w, v_w1, v_w2, fc2_w, wb);

    // 1) front: fc1 -> GRU -> lse1 -> lse2 -> me1 (+BN partials + hl)
    front<<<g1024, blk, 0, stream>>>(
        inputs, hidden, latent,
        wb + woff::fc1, fc1_b, wb + woff::ih, wb + woff::hh, b_ih, b_hh,
        wb + woff::l1, lse_b1, wb + woff::l2, lse_b2,
        wb + woff::m1, me_b1, wb + woff::f2, fc2_b,
        hb, t1b, psum, psq, hlf);

    // 2) BN finalize
    bn_final_kernel<<<dim3(256), blk, 0, stream>>>(psum, psq, me_g, me_beta, scale, shift);

    // 3) back: me2 -> pm -> kq -> v1 -> v2 -> vproj -> softmax -> out
    back<<<g1024, blk, 0, stream>>>(
        t1b, scale, shift, wb + woff::m2, me_b2, eps,
        hb, wb + woff::kw, k_b, wb + woff::qw, q_b,
        wb + woff::v1, v_b1, wb + woff::v2, v_b2,
        fc2_w, hlf, (float*)d_out);
}

// Round 14
// 143.375 us; speedup vs baseline: 1.0714x; 1.0714x over previous
//
#include <hip/hip_runtime.h>
#include <math.h>

// Problem constants (fixed instance)
namespace {
constexpr int R_ = 32768;     // BS*N rows
constexpr int N_ = 16;
constexpr int NA_ = 30;
constexpr int BSB_ = R_ / N_; // 2048 batches
constexpr int NBLK_ = R_ / 32; // 1024 row-blocks (32 rows each)
}

typedef __bf16 bf16x8 __attribute__((ext_vector_type(8)));
typedef float f32x4 __attribute__((ext_vector_type(4)));

__device__ inline unsigned int f2bf(float f) {
    unsigned int u = __float_as_uint(f);
    return (u + 0x7fffu + ((u >> 16) & 1u)) >> 16;  // RTN-even
}
__device__ inline float bf2f(unsigned int us) {
    return __uint_as_float(us << 16);
}
__device__ inline unsigned int pack2(float a, float b) {
    return f2bf(a) | (f2bf(b) << 16);
}
__device__ inline uint4 pack8(float4 f0, float4 f1) {
    uint4 u;
    u.x = pack2(f0.x, f0.y); u.y = pack2(f0.z, f0.w);
    u.z = pack2(f1.x, f1.y); u.w = pack2(f1.z, f1.w);
    return u;
}
// Fast transcendentals (v_exp/v_rcp); rel err ~2^-21 << bf16 rounding 2^-9.
__device__ inline float fsig(float x)  { return __builtin_amdgcn_rcpf(1.f + __expf(-x)); }
__device__ inline float ftanh(float x) { return 1.f - 2.f * __builtin_amdgcn_rcpf(__expf(2.f * x) + 1.f); }

// A fragment from swizzled LDS tile (KC = 16B-chunks per row)
__device__ __forceinline__ bf16x8 lda_frag(const uint4* At, int KC, int row, int c) {
    return __builtin_bit_cast(bf16x8, At[(row * KC + c) ^ (row & 7)]);
}
// B fragment direct from global bf16 weights
__device__ __forceinline__ bf16x8 ldb_frag(const unsigned short* W, int row, int rstride, int c) {
    return __builtin_bit_cast(bf16x8, *(const uint4*)(W + (size_t)row * rstride + (size_t)c * 8));
}

// ---------------------------------------------------------------------------
// One-shot weight conversion f32 -> bf16 into workspace (concatenated).
namespace woff {
constexpr unsigned fc1 = 0;
constexpr unsigned ih  = 16384;
constexpr unsigned hh  = 65536;
constexpr unsigned l1  = 114688;
constexpr unsigned l2  = 122880;
constexpr unsigned m1  = 139264;
constexpr unsigned m2  = 204800;
constexpr unsigned kw  = 237568;
constexpr unsigned qw  = 241664;
constexpr unsigned v1  = 243712;
constexpr unsigned v2  = 292864;
constexpr unsigned f2  = 309248;
constexpr unsigned total = 347648;
}

__global__ __launch_bounds__(256)
void wcvt_kernel(const float* __restrict__ fc1_w, const float* __restrict__ w_ih,
                 const float* __restrict__ w_hh, const float* __restrict__ lse_w1,
                 const float* __restrict__ lse_w2, const float* __restrict__ me_w1,
                 const float* __restrict__ me_w2, const float* __restrict__ k_w,
                 const float* __restrict__ q_w, const float* __restrict__ v_w1,
                 const float* __restrict__ v_w2, const float* __restrict__ fc2_w,
                 unsigned short* __restrict__ dst)
{
    unsigned i = blockIdx.x * 256 + threadIdx.x;
    if (i >= woff::total) return;
    const float* src; unsigned base;
    if      (i < woff::ih) { src = fc1_w;  base = woff::fc1; }
    else if (i < woff::hh) { src = w_ih;   base = woff::ih; }
    else if (i < woff::l1) { src = w_hh;   base = woff::hh; }
    else if (i < woff::l2) { src = lse_w1; base = woff::l1; }
    else if (i < woff::m1) { src = lse_w2; base = woff::l2; }
    else if (i < woff::m2) { src = me_w1;  base = woff::m1; }
    else if (i < woff::kw) { src = me_w2;  base = woff::m2; }
    else if (i < woff::qw) { src = k_w;    base = woff::kw; }
    else if (i < woff::v1) { src = q_w;    base = woff::qw; }
    else if (i < woff::v2) { src = v_w1;   base = woff::v1; }
    else if (i < woff::f2) { src = v_w2;   base = woff::v2; }
    else                   { src = fc2_w;  base = woff::f2; }
    dst[i] = (unsigned short)f2bf(src[i - base]);
}

// ---------------------------------------------------------------------------
// Merged stage 1, 512 threads / 8 waves (each wave: 16-col strip -> small
// accumulator state, <=64 regs/wave incl. AGPR, so 8 waves/SIMD can reside).
// Blocks [0,1024): fc1+GRU. Blocks [1024,2048): lse1+lse2. 32-row tiles.
__global__ __launch_bounds__(512, 8)
void stage1(const float* __restrict__ inputs, const float* __restrict__ hidden,
            const unsigned short* __restrict__ fc1w, const float* __restrict__ fc1_b,
            const unsigned short* __restrict__ wih, const unsigned short* __restrict__ whh,
            const float* __restrict__ b_ih, const float* __restrict__ b_hh,
            unsigned short* __restrict__ hb,
            const float* __restrict__ latent,
            const unsigned short* __restrict__ w1b, const float* __restrict__ b1,
            const unsigned short* __restrict__ w2b, const float* __restrict__ b2,
            unsigned short* __restrict__ leb)
{
    __shared__ uint4 shbuf[32 * 48];   // 24 KB, unioned between both paths
    const int tid = threadIdx.x;
    const int lane = tid & 63, w = tid >> 6;      // w: 0..7
    const int m = lane & 15, g = lane >> 4;

    if (blockIdx.x < (unsigned)NBLK_) {
        // ================= fc1 + GRU =================
        uint4* Ain   = shbuf;            // 32x16: inputs bf16
        uint4* Atile = shbuf + 32 * 16;  // 32x32: [x | hidden] bf16
        const int r0 = blockIdx.x * 32;

        {   // 512 threads: one uint4 each for inputs and hidden
            int row = tid >> 4, c = tid & 15;
            const float4* p = (const float4*)(inputs + (size_t)(r0 + row) * 128 + c * 8);
            Ain[(row * 16 + c) ^ (row & 7)] = pack8(p[0], p[1]);
            const float4* ph = (const float4*)(hidden + (size_t)(r0 + row) * 128 + c * 8);
            Atile[(row * 32 + (16 + c)) ^ (row & 7)] = pack8(ph[0], ph[1]);
        }
        __syncthreads();

        // ---- phase 1: x = relu(fc1); wave w: cols w*16..w*16+15 ----
        {
            f32x4 acc[2] = {};
            #pragma unroll
            for (int ks = 0; ks < 4; ++ks) {
                bf16x8 bf = ldb_frag(fc1w, w * 16 + m, 128, ks * 4 + g);
                #pragma unroll
                for (int fr = 0; fr < 2; ++fr) {
                    bf16x8 af = lda_frag(Ain, 16, fr * 16 + m, ks * 4 + g);
                    acc[fr] = __builtin_amdgcn_mfma_f32_16x16x32_bf16(af, bf, acc[fr], 0, 0, 0);
                }
            }
            int col = w * 16 + m;
            float bv = fc1_b[col];
            int c = col >> 3, el = col & 7;
            #pragma unroll
            for (int fr = 0; fr < 2; ++fr) {
                #pragma unroll
                for (int i = 0; i < 4; ++i) {
                    int row = fr * 16 + g * 4 + i;
                    float v = acc[fr][i] + bv;
                    v = v > 0.f ? v : 0.f;
                    ((unsigned short*)Atile)[((row * 32 + c) ^ (row & 7)) * 8 + el] =
                        (unsigned short)f2bf(v);
                }
            }
        }
        __syncthreads();

        // ---- phase 2: GRU; wave w: gate cols w*16..w*16+15 of each gate ----
        {
            f32x4 rr[2] = {}, zz[2] = {}, ni[2] = {}, nh[2] = {};
            const int ro = w * 16 + m;
            #pragma unroll
            for (int ks = 0; ks < 4; ++ks) {  // x part: wih
                bf16x8 brr = ldb_frag(wih, ro, 128, ks * 4 + g);
                bf16x8 bzz = ldb_frag(wih, 128 + ro, 128, ks * 4 + g);
                bf16x8 bnn = ldb_frag(wih, 256 + ro, 128, ks * 4 + g);
                #pragma unroll
                for (int fr = 0; fr < 2; ++fr) {
                    bf16x8 af = lda_frag(Atile, 32, fr * 16 + m, ks * 4 + g);
                    rr[fr] = __builtin_amdgcn_mfma_f32_16x16x32_bf16(af, brr, rr[fr], 0, 0, 0);
                    zz[fr] = __builtin_amdgcn_mfma_f32_16x16x32_bf16(af, bzz, zz[fr], 0, 0, 0);
                    ni[fr] = __builtin_amdgcn_mfma_f32_16x16x32_bf16(af, bnn, ni[fr], 0, 0, 0);
                }
            }
            #pragma unroll
            for (int ks = 0; ks < 4; ++ks) {  // hidden part: whh
                bf16x8 brr = ldb_frag(whh, ro, 128, ks * 4 + g);
                bf16x8 bzz = ldb_frag(whh, 128 + ro, 128, ks * 4 + g);
                bf16x8 bnn = ldb_frag(whh, 256 + ro, 128, ks * 4 + g);
                #pragma unroll
                for (int fr = 0; fr < 2; ++fr) {
                    bf16x8 af = lda_frag(Atile, 32, fr * 16 + m, 16 + ks * 4 + g);
                    rr[fr] = __builtin_amdgcn_mfma_f32_16x16x32_bf16(af, brr, rr[fr], 0, 0, 0);
                    zz[fr] = __builtin_amdgcn_mfma_f32_16x16x32_bf16(af, bzz, zz[fr], 0, 0, 0);
                    nh[fr] = __builtin_amdgcn_mfma_f32_16x16x32_bf16(af, bnn, nh[fr], 0, 0, 0);
                }
            }
            {
                int c = ro;   // 0..127
                float brz = b_ih[c] + b_hh[c];
                float bzz2 = b_ih[128 + c] + b_hh[128 + c];
                float bin = b_ih[256 + c], bhn = b_hh[256 + c];
                int hc = 16 + (c >> 3), hel = c & 7;  // hidden chunk in Atile
                #pragma unroll
                for (int fr = 0; fr < 2; ++fr) {
                    #pragma unroll
                    for (int i = 0; i < 4; ++i) {
                        int row = fr * 16 + g * 4 + i;
                        float rv = fsig(rr[fr][i] + brz);
                        float zv = fsig(zz[fr][i] + bzz2);
                        float ng = ftanh(ni[fr][i] + bin + rv * (nh[fr][i] + bhn));
                        float hp = bf2f(((unsigned short*)Atile)[((row * 32 + hc) ^ (row & 7)) * 8 + hel]);
                        float hv = ng + zv * (hp - ng);
                        hb[(size_t)(r0 + row) * 128 + c] = (unsigned short)f2bf(hv);
                    }
                }
            }
        }
    } else {
        // ================= lse1 + lse2 =================
        uint4* Alat = shbuf;            // 32x8
        uint4* Alt  = shbuf + 32 * 8;   // 32x16
        const int r0 = (blockIdx.x - NBLK_) * 32;

        if (tid < 256) {
            int row = tid >> 3, c = tid & 7;
            const float4* p = (const float4*)(latent + (size_t)(r0 + row) * 64 + c * 8);
            Alat[(row * 8 + c) ^ (row & 7)] = pack8(p[0], p[1]);
        }
        __syncthreads();

        // lse1: K=64, O=128; wave w: cols w*16 -> Alt
        {
            f32x4 acc[2] = {};
            #pragma unroll
            for (int ks = 0; ks < 2; ++ks) {
                bf16x8 bf = ldb_frag(w1b, w * 16 + m, 64, ks * 4 + g);
                #pragma unroll
                for (int fr = 0; fr < 2; ++fr) {
                    bf16x8 af = lda_frag(Alat, 8, fr * 16 + m, ks * 4 + g);
                    acc[fr] = __builtin_amdgcn_mfma_f32_16x16x32_bf16(af, bf, acc[fr], 0, 0, 0);
                }
            }
            int col = w * 16 + m;
            float bv = b1[col];
            int c = col >> 3, el = col & 7;
            #pragma unroll
            for (int fr = 0; fr < 2; ++fr) {
                #pragma unroll
                for (int i = 0; i < 4; ++i) {
                    int row = fr * 16 + g * 4 + i;
                    float v = acc[fr][i] + bv;
                    v = v > 0.f ? v : 0.f;
                    ((unsigned short*)Alt)[((row * 16 + c) ^ (row & 7)) * 8 + el] =
                        (unsigned short)f2bf(v);
                }
            }
        }
        __syncthreads();

        // lse2: K=128, O=128 -> leb
        {
            f32x4 acc[2] = {};
            #pragma unroll
            for (int ks = 0; ks < 4; ++ks) {
                bf16x8 bf = ldb_frag(w2b, w * 16 + m, 128, ks * 4 + g);
                #pragma unroll
                for (int fr = 0; fr < 2; ++fr) {
                    bf16x8 af = lda_frag(Alt, 16, fr * 16 + m, ks * 4 + g);
                    acc[fr] = __builtin_amdgcn_mfma_f32_16x16x32_bf16(af, bf, acc[fr], 0, 0, 0);
                }
            }
            int col = w * 16 + m;
            float bv = b2[col];
            #pragma unroll
            for (int fr = 0; fr < 2; ++fr) {
                #pragma unroll
                for (int i = 0; i < 4; ++i) {
                    int rowl = fr * 16 + g * 4 + i;
                    float v = acc[fr][i] + bv;
                    leb[(size_t)(r0 + rowl) * 128 + col] = (unsigned short)f2bf(v);
                }
            }
        }
    }
}

// ---------------------------------------------------------------------------
// me1 GEMM (K=256, O=256) + BN partial sums + fused hl projection, 32-row blocks.
__global__ __launch_bounds__(256, 4)
void me1_stats(const unsigned short* __restrict__ hb, const unsigned short* __restrict__ leb,
               const unsigned short* __restrict__ W, const float* __restrict__ bias,
               const unsigned short* __restrict__ f2w, const float* __restrict__ fc2_b,
               unsigned short* __restrict__ t1,
               float* __restrict__ psum, float* __restrict__ psq,
               float* __restrict__ hl)
{
    __shared__ uint4 Atile[32 * 32];
    __shared__ uint4 T1b[32 * 32];   // t1 bounce (linear 32x256 bf16)
    const int tid = threadIdx.x;
    const int r0 = blockIdx.x * 32;

    for (int idx = tid; idx < 32 * 16; idx += 256) {
        int row = idx >> 4, c = idx & 15;
        Atile[(row * 32 + c) ^ (row & 7)] =
            *(const uint4*)(hb + (size_t)(r0 + row) * 128 + c * 8);
        Atile[(row * 32 + (16 + c)) ^ (row & 7)] =
            *(const uint4*)(leb + (size_t)(r0 + row) * 128 + c * 8);
    }
    __syncthreads();

    const int lane = tid & 63, w = tid >> 6;
    const int m = lane & 15, g = lane >> 4;
    unsigned short* t1s = (unsigned short*)T1b;

    for (int ot = 0; ot < 2; ++ot) {
        const int o0 = ot * 128 + w * 32;
        f32x4 acc[2][2] = {};
        #pragma unroll
        for (int ks = 0; ks < 8; ++ks) {
            bf16x8 af[2], bf[2];
            #pragma unroll
            for (int fr = 0; fr < 2; ++fr)
                af[fr] = lda_frag(Atile, 32, fr * 16 + m, ks * 4 + g);
            #pragma unroll
            for (int fc = 0; fc < 2; ++fc)
                bf[fc] = ldb_frag(W, o0 + fc * 16 + m, 256, ks * 4 + g);
            #pragma unroll
            for (int fr = 0; fr < 2; ++fr)
                #pragma unroll
                for (int fc = 0; fc < 2; ++fc)
                    acc[fr][fc] = __builtin_amdgcn_mfma_f32_16x16x32_bf16(
                        af[fr], bf[fc], acc[fr][fc], 0, 0, 0);
        }
        #pragma unroll
        for (int fc = 0; fc < 2; ++fc) {
            int col = o0 + fc * 16 + m;
            float bv = bias[col];
            float s = 0.f, q = 0.f;
            #pragma unroll
            for (int fr = 0; fr < 2; ++fr) {
                #pragma unroll
                for (int i = 0; i < 4; ++i) {
                    int rowl = fr * 16 + g * 4 + i;
                    float v = acc[fr][fc][i] + bv;
                    t1s[rowl * 256 + col] = (unsigned short)f2bf(v);
                    s += v; q += v * v;
                }
            }
            s += __shfl_xor(s, 16); s += __shfl_xor(s, 32);  // over g (all 32 rows)
            q += __shfl_xor(q, 16); q += __shfl_xor(q, 32);
            if (lane < 16) {
                psum[(size_t)blockIdx.x * 256 + col] = s;
                psq[(size_t)blockIdx.x * 256 + col] = q;
            }
        }
    }
    __syncthreads();
    for (int idx = tid; idx < 32 * 32; idx += 256) {  // coalesced t1 store
        int row = idx >> 5, c = idx & 31;
        *(uint4*)(t1 + (size_t)(r0 + row) * 256 + c * 8) = T1b[row * 32 + c];
    }

    // ---- fused hl: waves 0-1 rows w*16..w*16+15, cols 0..29 ----
    if (w < 2) {
        f32x4 acc[2] = {};
        #pragma unroll
        for (int ks = 0; ks < 8; ++ks) {
            bf16x8 af = lda_frag(Atile, 32, w * 16 + m, ks * 4 + g);
            bf16x8 bf[2];
            #pragma unroll
            for (int fc = 0; fc < 2; ++fc) {
                int col = fc * 16 + m;
                bf[fc] = (col < NA_) ? ldb_frag(f2w, col, 1280, ks * 4 + g) : bf16x8{};
            }
            #pragma unroll
            for (int fc = 0; fc < 2; ++fc)
                acc[fc] = __builtin_amdgcn_mfma_f32_16x16x32_bf16(af, bf[fc], acc[fc], 0, 0, 0);
        }
        #pragma unroll
        for (int fc = 0; fc < 2; ++fc) {
            int col = fc * 16 + m;
            if (col < NA_) {
                float bv = fc2_b[col];
                #pragma unroll
                for (int i = 0; i < 4; ++i) {
                    int row = r0 + w * 16 + g * 4 + i;
                    hl[(size_t)row * NA_ + col] = acc[fc][i] + bv;
                }
            }
        }
    }
}

// ---------------------------------------------------------------------------
// Parallel BN finalize: one block per feature; threads stride over NBLK_.
__global__ __launch_bounds__(256)
void bn_final_kernel(const float* __restrict__ psum, const float* __restrict__ psq,
                     const float* __restrict__ g, const float* __restrict__ beta,
                     float* __restrict__ scale, float* __restrict__ shift)
{
    __shared__ float redS[4], redQ[4];
    const int f = blockIdx.x;
    const int tid = threadIdx.x;
    float s = 0.f, q = 0.f;
    for (int b = tid; b < NBLK_; b += 256) {
        s += psum[(size_t)b * 256 + f];
        q += psq[(size_t)b * 256 + f];
    }
    #pragma unroll
    for (int off = 32; off >= 1; off >>= 1) {
        s += __shfl_down(s, off);
        q += __shfl_down(q, off);
    }
    if ((tid & 63) == 0) { redS[tid >> 6] = s; redQ[tid >> 6] = q; }
    __syncthreads();
    if (tid == 0) {
        s = redS[0] + redS[1] + redS[2] + redS[3];
        q = redQ[0] + redQ[1] + redQ[2] + redQ[3];
        float mean = s / (float)R_;
        float var = q / (float)R_ - mean * mean;
        float istd = rsqrtf(var + 1e-5f);
        float sc = g[f] * istd;
        scale[f] = sc;
        shift[f] = beta[f] - mean * sc;
    }
}

// ---------------------------------------------------------------------------
// Fused me2 + kq_norm + v1 + v2 (pm never leaves LDS).
__global__ __launch_bounds__(256, 4)
void me2kqv(const unsigned short* __restrict__ t1,
            const float* __restrict__ scale, const float* __restrict__ shift,
            const unsigned short* __restrict__ W2, const float* __restrict__ me2_b,
            const float* __restrict__ eps,
            const unsigned short* __restrict__ hb,
            const unsigned short* __restrict__ kwb, const float* __restrict__ k_b,
            const unsigned short* __restrict__ qwb, const float* __restrict__ q_b,
            const unsigned short* __restrict__ v1w, const float* __restrict__ v1_b,
            const unsigned short* __restrict__ v2w, const float* __restrict__ v2_b,
            float* __restrict__ kh, float* __restrict__ qh,
            unsigned short* __restrict__ valb)
{
    __shared__ uint4 bufA[32 * 32];   // 16 KB: t1(BN) tile, then A3 (t3)
    __shared__ uint4 bufB[32 * 24];   // 12 KB: [h 0..15 | pm 16..23]; later val bounce
    __shared__ float sc_s[256], sh_s[256];
    const int tid = threadIdx.x;
    const int r0 = blockIdx.x * 32;

    sc_s[tid] = scale[tid];
    sh_s[tid] = shift[tid];
    for (int idx = tid; idx < 32 * 16; idx += 256) {
        int row = idx >> 4, c = idx & 15;
        bufB[(row * 24 + c) ^ (row & 7)] =
            *(const uint4*)(hb + (size_t)(r0 + row) * 128 + c * 8);
    }
    __syncthreads();

    // stage t1 with BN(scale/shift)+lrelu -> bufA (swizzled)
    for (int idx = tid; idx < 32 * 32; idx += 256) {
        int row = idx >> 5, c = idx & 31;
        uint4 u = *(const uint4*)(t1 + (size_t)(r0 + row) * 256 + c * 8);
        unsigned int vv[4] = {u.x, u.y, u.z, u.w};
        float f[8];
        #pragma unroll
        for (int q2 = 0; q2 < 4; ++q2) {
            f[2 * q2]     = __uint_as_float((vv[q2] & 0xffffu) << 16);
            f[2 * q2 + 1] = __uint_as_float(vv[q2] & 0xffff0000u);
        }
        int k = c * 8;
        #pragma unroll
        for (int j = 0; j < 8; ++j) {
            float v = f[j] * sc_s[k + j] + sh_s[k + j];
            f[j] = v > 0.f ? v : 0.01f * v;
        }
        uint4 r;
        r.x = pack2(f[0], f[1]); r.y = pack2(f[2], f[3]);
        r.z = pack2(f[4], f[5]); r.w = pack2(f[6], f[7]);
        bufA[(row * 32 + c) ^ (row & 7)] = r;
    }
    __syncthreads();

    const int lane = tid & 63, w = tid >> 6;
    const int m = lane & 15, g = lane >> 4;

    // ---- me2 GEMM: wave w owns mean col w*16+m (fc=0), std col 64+w*16+m ----
    {
        f32x4 acc[2][2] = {};
        #pragma unroll
        for (int ks = 0; ks < 8; ++ks) {
            bf16x8 af[2], bf[2];
            #pragma unroll
            for (int fr = 0; fr < 2; ++fr)
                af[fr] = lda_frag(bufA, 32, fr * 16 + m, ks * 4 + g);
            bf[0] = ldb_frag(W2, w * 16 + m, 256, ks * 4 + g);
            bf[1] = ldb_frag(W2, 64 + w * 16 + m, 256, ks * 4 + g);
            #pragma unroll
            for (int fr = 0; fr < 2; ++fr)
                #pragma unroll
                for (int fc = 0; fc < 2; ++fc)
                    acc[fr][fc] = __builtin_amdgcn_mfma_f32_16x16x32_bf16(
                        af[fr], bf[fc], acc[fr][fc], 0, 0, 0);
        }
        int cp = w * 16 + m;  // 0..63
        float bv0 = me2_b[cp], bv1 = me2_b[64 + cp];
        int hc = 16 + (cp >> 3), hel = cp & 7;
        #pragma unroll
        for (int fr = 0; fr < 2; ++fr) {
            #pragma unroll
            for (int i = 0; i < 4; ++i) {
                float vm = acc[fr][0][i] + bv0;
                vm = vm > 0.f ? vm : 0.01f * vm;
                vm = fminf(fmaxf(vm, -1.f), 1.f);
                float vs = acc[fr][1][i] + bv1;
                vs = vs > 0.f ? vs : 0.01f * vs;
                vs = fminf(fmaxf(vs, 0.5f), 1.f);
                int row = fr * 16 + g * 4 + i;
                float e = eps[(size_t)(r0 + row) * 64 + cp];
                ((unsigned short*)bufB)[((row * 24 + hc) ^ (row & 7)) * 8 + hel] =
                    (unsigned short)f2bf(vm + vs * e);
            }
        }
    }
    __syncthreads();   // pm visible in bufB; bufA (t1) dead

    // ---- phase 0: wave 0 -> kh, wave 1 -> qh ----
    if (w < 2) {
        const bool isq = (w == 1);
        f32x4 acc[2][2] = {};
        const int nks = isq ? 2 : 4;
        for (int ks = 0; ks < nks; ++ks) {
            bf16x8 af[2], bf[2];
            #pragma unroll
            for (int fr = 0; fr < 2; ++fr)
                af[fr] = lda_frag(bufB, 24, fr * 16 + m, (isq ? 16 : 0) + ks * 4 + g);
            #pragma unroll
            for (int fc = 0; fc < 2; ++fc)
                bf[fc] = isq ? ldb_frag(qwb, fc * 16 + m, 64, ks * 4 + g)
                             : ldb_frag(kwb, fc * 16 + m, 128, ks * 4 + g);
            #pragma unroll
            for (int fr = 0; fr < 2; ++fr)
                #pragma unroll
                for (int fc = 0; fc < 2; ++fc)
                    acc[fr][fc] = __builtin_amdgcn_mfma_f32_16x16x32_bf16(
                        af[fr], bf[fc], acc[fr][fc], 0, 0, 0);
        }
        const float* bias = isq ? q_b : k_b;
        float b0 = bias[m], b1 = bias[16 + m];
        float* outp = isq ? qh : kh;
        #pragma unroll
        for (int fr = 0; fr < 2; ++fr) {
            #pragma unroll
            for (int i = 0; i < 4; ++i) {
                float v0 = acc[fr][0][i] + b0;
                float v1 = acc[fr][1][i] + b1;
                float ss = v0 * v0 + v1 * v1;
                ss += __shfl_xor(ss, 1); ss += __shfl_xor(ss, 2);
                ss += __shfl_xor(ss, 4); ss += __shfl_xor(ss, 8);
                float inv = 1.f / fmaxf(sqrtf(ss), 1e-8f);
                int row = r0 + fr * 16 + g * 4 + i;
                outp[(size_t)row * 32 + m] = v0 * inv;
                outp[(size_t)row * 32 + 16 + m] = v1 * inv;
            }
        }
    }

    // ---- phase 1: v1 (K=192, O=256) -> bufA as A3 ----
    for (int ot = 0; ot < 2; ++ot) {
        const int o0 = ot * 128 + w * 32;
        f32x4 acc[2][2] = {};
        #pragma unroll
        for (int ks = 0; ks < 6; ++ks) {
            bf16x8 af[2], bf[2];
            #pragma unroll
            for (int fr = 0; fr < 2; ++fr)
                af[fr] = lda_frag(bufB, 24, fr * 16 + m, ks * 4 + g);
            #pragma unroll
            for (int fc = 0; fc < 2; ++fc)
                bf[fc] = ldb_frag(v1w, o0 + fc * 16 + m, 192, ks * 4 + g);
            #pragma unroll
            for (int fr = 0; fr < 2; ++fr)
                #pragma unroll
                for (int fc = 0; fc < 2; ++fc)
                    acc[fr][fc] = __builtin_amdgcn_mfma_f32_16x16x32_bf16(
                        af[fr], bf[fc], acc[fr][fc], 0, 0, 0);
        }
        #pragma unroll
        for (int fc = 0; fc < 2; ++fc) {
            int col = o0 + fc * 16 + m;
            float bv = v1_b[col];
            int c = col >> 3, el = col & 7;
            #pragma unroll
            for (int fr = 0; fr < 2; ++fr) {
                #pragma unroll
                for (int i = 0; i < 4; ++i) {
                    int row = fr * 16 + g * 4 + i;
                    float v = acc[fr][fc][i] + bv;
                    v = v > 0.f ? v : 0.01f * v;
                    ((unsigned short*)bufA)[((row * 32 + c) ^ (row & 7)) * 8 + el] =
                        (unsigned short)f2bf(v);
                }
            }
        }
    }
    __syncthreads();

    // ---- phase 2: v2 (K=256, O=64); wave w: cols w*16; bounce -> coalesced ----
    {
        f32x4 acc[2] = {};
        #pragma unroll
        for (int ks = 0; ks < 8; ++ks) {
            bf16x8 af[2];
            #pragma unroll
            for (int fr = 0; fr < 2; ++fr)
                af[fr] = lda_frag(bufA, 32, fr * 16 + m, ks * 4 + g);
            bf16x8 bf = ldb_frag(v2w, w * 16 + m, 256, ks * 4 + g);
            #pragma unroll
            for (int fr = 0; fr < 2; ++fr)
                acc[fr] = __builtin_amdgcn_mfma_f32_16x16x32_bf16(af[fr], bf, acc[fr], 0, 0, 0);
        }
        int col = w * 16 + m;
        float bv = v2_b[col];
        unsigned short* vb = (unsigned short*)bufB;  // bufB dead after v1
        #pragma unroll
        for (int fr = 0; fr < 2; ++fr) {
            #pragma unroll
            for (int i = 0; i < 4; ++i) {
                int rowl = fr * 16 + g * 4 + i;
                vb[rowl * 64 + col] = (unsigned short)f2bf(acc[fr][i] + bv);
            }
        }
    }
    __syncthreads();
    {   // 32x64 bf16 = 256 uint4: one per thread
        int row = tid >> 3, c = tid & 7;
        *(uint4*)(valb + (size_t)(r0 + row) * 64 + c * 8) = ((uint4*)bufB)[row * 8 + c];
    }
}

// ---------------------------------------------------------------------------
// vproj[r][na] = w2[na, 256+64*(r%16) .. +64] . value[r]   (value bf16, w2 f32)
__global__ __launch_bounds__(256)
void vproj_kernel(const unsigned short* __restrict__ value, const float* __restrict__ w2,
                  float* __restrict__ vproj)
{
    __shared__ float w2s[NA_][65];
    __shared__ float val_s[64][65];
    const int tid = threadIdx.x;
    const int j = blockIdx.x & 15;
    const int b0 = (blockIdx.x >> 4) * 64;

    for (int idx = tid; idx < NA_ * 64; idx += 256) {
        int na = idx >> 6, k = idx & 63;
        w2s[na][k] = w2[(size_t)na * 1280 + 256 + j * 64 + k];
    }
    for (int idx = tid; idx < 64 * 64; idx += 256) {
        int bl = idx >> 6, k = idx & 63;
        val_s[bl][k] = bf2f(value[((size_t)(b0 + bl) * 16 + j) * 64 + k]);
    }
    __syncthreads();

    for (int task = tid; task < 64 * NA_; task += 256) {
        int bl = task / NA_, na = task - bl * NA_;
        float acc = 0.f;
        #pragma unroll 16
        for (int k = 0; k < 64; ++k) acc = fmaf(val_s[bl][k], w2s[na][k], acc);
        vproj[((size_t)(b0 + bl) * 16 + j) * NA_ + na] = acc;
    }
}

// Per batch: cosine logits (16x16), softmax over j, zero diag, combine.
__global__ __launch_bounds__(256)
void attn_combine(const float* __restrict__ kh, const float* __restrict__ qh,
                  const float* __restrict__ vproj, const float* __restrict__ hl,
                  float* __restrict__ outv)
{
    __shared__ float kh_s[16][33], qh_s[16][33];
    __shared__ float al_s[16][16];
    __shared__ float vp_s[16][NA_];
    const int tid = threadIdx.x;
    const size_t rb = (size_t)blockIdx.x * 16;

    for (int idx = tid; idx < 512; idx += 256) {
        int r = idx >> 5, a = idx & 31;
        kh_s[r][a] = kh[rb * 32 + idx];
        qh_s[r][a] = qh[rb * 32 + idx];
    }
    for (int idx = tid; idx < 16 * NA_; idx += 256)
        vp_s[idx / NA_][idx % NA_] = vproj[rb * NA_ + idx];
    __syncthreads();

    {
        int i = tid >> 4, j = tid & 15;
        float l = 0.f;
        #pragma unroll
        for (int a = 0; a < 32; ++a) l = fmaf(kh_s[i][a], qh_s[j][a], l);
        float mx = l;
        #pragma unroll
        for (int mm = 8; mm >= 1; mm >>= 1) mx = fmaxf(mx, __shfl_xor(mx, mm));
        float e = __expf(l - mx);
        float s = e;
        #pragma unroll
        for (int mm = 8; mm >= 1; mm >>= 1) s += __shfl_xor(s, mm);
        float a = e / s;
        if (i == j) a = 0.f;
        al_s[i][j] = a;
    }
    __syncthreads();

    for (int task = tid; task < 16 * NA_; task += 256) {
        int i = task / NA_, na = task - i * NA_;
        float acc = hl[(rb + i) * NA_ + na];
        #pragma unroll
        for (int j = 0; j < 16; ++j) acc = fmaf(al_s[i][j], vp_s[j][na], acc);
        outv[(rb + i) * NA_ + na] = acc;
    }
}

extern "C" void kernel_launch(void* const* d_in, const int* in_sizes, int n_in,
                              void* d_out, int out_size, void* d_ws, size_t ws_size,
                              hipStream_t stream)
{
    (void)in_sizes; (void)n_in; (void)out_size; (void)ws_size;
    const float* inputs  = (const float*)d_in[0];
    const float* hidden  = (const float*)d_in[1];
    const float* latent  = (const float*)d_in[2];
    const float* eps     = (const float*)d_in[3];
    const float* fc1_w   = (const float*)d_in[4];
    const float* fc1_b   = (const float*)d_in[5];
    const float* w_ih    = (const float*)d_in[6];
    const float* w_hh    = (const float*)d_in[7];
    const float* b_ih    = (const float*)d_in[8];
    const float* b_hh    = (const float*)d_in[9];
    const float* lse_w1  = (const float*)d_in[10];
    const float* lse_b1  = (const float*)d_in[11];
    const float* lse_w2  = (const float*)d_in[12];
    const float* lse_b2  = (const float*)d_in[13];
    const float* me_w1   = (const float*)d_in[14];
    const float* me_b1   = (const float*)d_in[15];
    const float* me_g    = (const float*)d_in[16];
    const float* me_beta = (const float*)d_in[17];
    const float* me_w2   = (const float*)d_in[18];
    const float* me_b2   = (const float*)d_in[19];
    const float* k_w     = (const float*)d_in[20];
    const float* k_b     = (const float*)d_in[21];
    const float* q_w     = (const float*)d_in[22];
    const float* q_b     = (const float*)d_in[23];
    const float* v_w1    = (const float*)d_in[24];
    const float* v_b1    = (const float*)d_in[25];
    const float* v_w2    = (const float*)d_in[26];
    const float* v_b2    = (const float*)d_in[27];
    const float* fc2_w   = (const float*)d_in[28];
    const float* fc2_b   = (const float*)d_in[29];

    const size_t R = R_;
    // Workspace layout: bf16 activations, bf16 weights, then f32 buffers.
    unsigned short* bws = (unsigned short*)d_ws;
    unsigned short* hb   = bws;               // R*128
    unsigned short* leb  = hb + R * 128;      // R*128
    unsigned short* t1b  = leb + R * 128;     // R*256
    unsigned short* valb = t1b + R * 256;     // R*64
    unsigned short* wb   = valb + R * 64;     // 347648 (bf16 weights)
    float* fws  = (float*)(wb + woff::total);
    float* khf  = fws;                 // R*32
    float* qhf  = khf + R * 32;        // R*32
    float* hlf  = qhf + R * 32;        // R*30
    float* vpf  = hlf + R * 30;        // R*30
    float* psum = vpf + R * 30;        // NBLK_*256
    float* psq  = psum + (size_t)NBLK_ * 256;
    float* scale = psq + (size_t)NBLK_ * 256;
    float* shift = scale + 256;

    dim3 blk(256);
    dim3 g1024(NBLK_);

    // 0) weights -> bf16 (once per call; cheap)
    wcvt_kernel<<<dim3((woff::total + 255) / 256), blk, 0, stream>>>(
        fc1_w, w_ih, w_hh, lse_w1, lse_w2, me_w1, me_w2, k_w, q_w, v_w1, v_w2, fc2_w, wb);

    // 1) merged stage1 (512 threads, 8 waves, <=64 regs/wave):
    //    fc1+GRU (blocks 0..1023), lse1+lse2 (blocks 1024..2047)
    stage1<<<dim3(2 * NBLK_), dim3(512), 0, stream>>>(
        inputs, hidden, wb + woff::fc1, fc1_b, wb + woff::ih, wb + woff::hh,
        b_ih, b_hh, hb,
        latent, wb + woff::l1, lse_b1, wb + woff::l2, lse_b2, leb);
    // 2) t1 = me1(cat(h,le)) -> bf16 + BN partial stats + hl projection
    me1_stats<<<g1024, blk, 0, stream>>>(hb, leb, wb + woff::m1, me_b1,
                                         wb + woff::f2, fc2_b, t1b, psum, psq, hlf);
    // 2b) BN finalize (parallel: one block per feature)
    bn_final_kernel<<<dim3(256), blk, 0, stream>>>(psum, psq, me_g, me_beta, scale, shift);
    // 3) fused me2(BN(t1)) -> pm [LDS] -> kq_norm + v1 + v2 -> kh/qh/value
    me2kqv<<<g1024, blk, 0, stream>>>(t1b, scale, shift, wb + woff::m2, me_b2, eps,
                                      hb, wb + woff::kw, k_b, wb + woff::qw, q_b,
                                      wb + woff::v1, v_b1, wb + woff::v2, v_b2,
                                      khf, qhf, valb);
    // 4) vproj = per-agent fc2_w slice . value
    vproj_kernel<<<dim3(16 * (BSB_ / 64)), blk, 0, stream>>>(valb, fc2_w, vpf);
    // 5) softmax + combine -> out
    attn_combine<<<dim3(BSB_), blk, 0, stream>>>(khf, qhf, vpf, hlf, (float*)d_out);
}

// Round 15
// 137.710 us; speedup vs baseline: 1.1155x; 1.0411x over previous
//
#include <hip/hip_runtime.h>
#include <math.h>

// Problem constants (fixed instance)
namespace {
constexpr int R_ = 32768;     // BS*N rows
constexpr int N_ = 16;
constexpr int NA_ = 30;
constexpr int BSB_ = R_ / N_; // 2048 batches
constexpr int NBLK_ = R_ / 32; // 1024 row-blocks (32 rows each)
}

typedef __bf16 bf16x8 __attribute__((ext_vector_type(8)));
typedef float f32x4 __attribute__((ext_vector_type(4)));

__device__ inline unsigned int f2bf(float f) {
    unsigned int u = __float_as_uint(f);
    return (u + 0x7fffu + ((u >> 16) & 1u)) >> 16;  // RTN-even
}
__device__ inline float bf2f(unsigned int us) {
    return __uint_as_float(us << 16);
}
__device__ inline unsigned int pack2(float a, float b) {
    return f2bf(a) | (f2bf(b) << 16);
}
__device__ inline uint4 pack8(float4 f0, float4 f1) {
    uint4 u;
    u.x = pack2(f0.x, f0.y); u.y = pack2(f0.z, f0.w);
    u.z = pack2(f1.x, f1.y); u.w = pack2(f1.z, f1.w);
    return u;
}
// Fast transcendentals (v_exp/v_rcp); rel err ~2^-21 << bf16 rounding 2^-9.
__device__ inline float fsig(float x)  { return __builtin_amdgcn_rcpf(1.f + __expf(-x)); }
__device__ inline float ftanh(float x) { return 1.f - 2.f * __builtin_amdgcn_rcpf(__expf(2.f * x) + 1.f); }

// A fragment from swizzled LDS tile (KC = 16B-chunks per row)
__device__ __forceinline__ bf16x8 lda_frag(const uint4* At, int KC, int row, int c) {
    return __builtin_bit_cast(bf16x8, At[(row * KC + c) ^ (row & 7)]);
}
// B fragment direct from global bf16 weights
__device__ __forceinline__ bf16x8 ldb_frag(const unsigned short* W, int row, int rstride, int c) {
    return __builtin_bit_cast(bf16x8, *(const uint4*)(W + (size_t)row * rstride + (size_t)c * 8));
}

// ---------------------------------------------------------------------------
// One-shot weight conversion f32 -> bf16 into workspace (concatenated).
namespace woff {
constexpr unsigned fc1 = 0;
constexpr unsigned ih  = 16384;
constexpr unsigned hh  = 65536;
constexpr unsigned l1  = 114688;
constexpr unsigned l2  = 122880;
constexpr unsigned m1  = 139264;
constexpr unsigned m2  = 204800;
constexpr unsigned kw  = 237568;
constexpr unsigned qw  = 241664;
constexpr unsigned v1  = 243712;
constexpr unsigned v2  = 292864;
constexpr unsigned f2  = 309248;
constexpr unsigned total = 347648;
}

__global__ __launch_bounds__(256)
void wcvt_kernel(const float* __restrict__ fc1_w, const float* __restrict__ w_ih,
                 const float* __restrict__ w_hh, const float* __restrict__ lse_w1,
                 const float* __restrict__ lse_w2, const float* __restrict__ me_w1,
                 const float* __restrict__ me_w2, const float* __restrict__ k_w,
                 const float* __restrict__ q_w, const float* __restrict__ v_w1,
                 const float* __restrict__ v_w2, const float* __restrict__ fc2_w,
                 unsigned short* __restrict__ dst)
{
    unsigned i = blockIdx.x * 256 + threadIdx.x;
    if (i >= woff::total) return;
    const float* src; unsigned base;
    if      (i < woff::ih) { src = fc1_w;  base = woff::fc1; }
    else if (i < woff::hh) { src = w_ih;   base = woff::ih; }
    else if (i < woff::l1) { src = w_hh;   base = woff::hh; }
    else if (i < woff::l2) { src = lse_w1; base = woff::l1; }
    else if (i < woff::m1) { src = lse_w2; base = woff::l2; }
    else if (i < woff::m2) { src = me_w1;  base = woff::m1; }
    else if (i < woff::kw) { src = me_w2;  base = woff::m2; }
    else if (i < woff::qw) { src = k_w;    base = woff::kw; }
    else if (i < woff::v1) { src = q_w;    base = woff::qw; }
    else if (i < woff::v2) { src = v_w1;   base = woff::v1; }
    else if (i < woff::f2) { src = v_w2;   base = woff::v2; }
    else                   { src = fc2_w;  base = woff::f2; }
    dst[i] = (unsigned short)f2bf(src[i - base]);
}

// ---------------------------------------------------------------------------
// Merged stage 1, 512 threads / 8 waves (each wave: 16-col strip).
// (512,6): 84-reg cap fits the ~80-reg GRU wave (incl. 32 AGPR acc) without
// spill; 24 waves/CU vs 16 at (256,4). (512,8)'s 64-cap spilled 55 MB (r14).
// Blocks [0,1024): fc1+GRU. Blocks [1024,2048): lse1+lse2. 32-row tiles.
__global__ __launch_bounds__(512, 6)
void stage1(const float* __restrict__ inputs, const float* __restrict__ hidden,
            const unsigned short* __restrict__ fc1w, const float* __restrict__ fc1_b,
            const unsigned short* __restrict__ wih, const unsigned short* __restrict__ whh,
            const float* __restrict__ b_ih, const float* __restrict__ b_hh,
            unsigned short* __restrict__ hb,
            const float* __restrict__ latent,
            const unsigned short* __restrict__ w1b, const float* __restrict__ b1,
            const unsigned short* __restrict__ w2b, const float* __restrict__ b2,
            unsigned short* __restrict__ leb)
{
    __shared__ uint4 shbuf[32 * 48];   // 24 KB, unioned between both paths
    const int tid = threadIdx.x;
    const int lane = tid & 63, w = tid >> 6;      // w: 0..7
    const int m = lane & 15, g = lane >> 4;

    if (blockIdx.x < (unsigned)NBLK_) {
        // ================= fc1 + GRU =================
        uint4* Ain   = shbuf;            // 32x16: inputs bf16
        uint4* Atile = shbuf + 32 * 16;  // 32x32: [x | hidden] bf16
        const int r0 = blockIdx.x * 32;

        {   // 512 threads: one uint4 each for inputs and hidden
            int row = tid >> 4, c = tid & 15;
            const float4* p = (const float4*)(inputs + (size_t)(r0 + row) * 128 + c * 8);
            Ain[(row * 16 + c) ^ (row & 7)] = pack8(p[0], p[1]);
            const float4* ph = (const float4*)(hidden + (size_t)(r0 + row) * 128 + c * 8);
            Atile[(row * 32 + (16 + c)) ^ (row & 7)] = pack8(ph[0], ph[1]);
        }
        __syncthreads();

        // ---- phase 1: x = relu(fc1); wave w: cols w*16..w*16+15 ----
        {
            f32x4 acc[2] = {};
            #pragma unroll
            for (int ks = 0; ks < 4; ++ks) {
                bf16x8 bf = ldb_frag(fc1w, w * 16 + m, 128, ks * 4 + g);
                #pragma unroll
                for (int fr = 0; fr < 2; ++fr) {
                    bf16x8 af = lda_frag(Ain, 16, fr * 16 + m, ks * 4 + g);
                    acc[fr] = __builtin_amdgcn_mfma_f32_16x16x32_bf16(af, bf, acc[fr], 0, 0, 0);
                }
            }
            int col = w * 16 + m;
            float bv = fc1_b[col];
            int c = col >> 3, el = col & 7;
            #pragma unroll
            for (int fr = 0; fr < 2; ++fr) {
                #pragma unroll
                for (int i = 0; i < 4; ++i) {
                    int row = fr * 16 + g * 4 + i;
                    float v = acc[fr][i] + bv;
                    v = v > 0.f ? v : 0.f;
                    ((unsigned short*)Atile)[((row * 32 + c) ^ (row & 7)) * 8 + el] =
                        (unsigned short)f2bf(v);
                }
            }
        }
        __syncthreads();

        // ---- phase 2: GRU; wave w: gate cols w*16..w*16+15 of each gate ----
        {
            f32x4 rr[2] = {}, zz[2] = {}, ni[2] = {}, nh[2] = {};
            const int ro = w * 16 + m;
            #pragma unroll
            for (int ks = 0; ks < 4; ++ks) {  // x part: wih
                bf16x8 brr = ldb_frag(wih, ro, 128, ks * 4 + g);
                bf16x8 bzz = ldb_frag(wih, 128 + ro, 128, ks * 4 + g);
                bf16x8 bnn = ldb_frag(wih, 256 + ro, 128, ks * 4 + g);
                #pragma unroll
                for (int fr = 0; fr < 2; ++fr) {
                    bf16x8 af = lda_frag(Atile, 32, fr * 16 + m, ks * 4 + g);
                    rr[fr] = __builtin_amdgcn_mfma_f32_16x16x32_bf16(af, brr, rr[fr], 0, 0, 0);
                    zz[fr] = __builtin_amdgcn_mfma_f32_16x16x32_bf16(af, bzz, zz[fr], 0, 0, 0);
                    ni[fr] = __builtin_amdgcn_mfma_f32_16x16x32_bf16(af, bnn, ni[fr], 0, 0, 0);
                }
            }
            #pragma unroll
            for (int ks = 0; ks < 4; ++ks) {  // hidden part: whh
                bf16x8 brr = ldb_frag(whh, ro, 128, ks * 4 + g);
                bf16x8 bzz = ldb_frag(whh, 128 + ro, 128, ks * 4 + g);
                bf16x8 bnn = ldb_frag(whh, 256 + ro, 128, ks * 4 + g);
                #pragma unroll
                for (int fr = 0; fr < 2; ++fr) {
                    bf16x8 af = lda_frag(Atile, 32, fr * 16 + m, 16 + ks * 4 + g);
                    rr[fr] = __builtin_amdgcn_mfma_f32_16x16x32_bf16(af, brr, rr[fr], 0, 0, 0);
                    zz[fr] = __builtin_amdgcn_mfma_f32_16x16x32_bf16(af, bzz, zz[fr], 0, 0, 0);
                    nh[fr] = __builtin_amdgcn_mfma_f32_16x16x32_bf16(af, bnn, nh[fr], 0, 0, 0);
                }
            }
            {
                int c = ro;   // 0..127
                float brz = b_ih[c] + b_hh[c];
                float bzz2 = b_ih[128 + c] + b_hh[128 + c];
                float bin = b_ih[256 + c], bhn = b_hh[256 + c];
                int hc = 16 + (c >> 3), hel = c & 7;  // hidden chunk in Atile
                #pragma unroll
                for (int fr = 0; fr < 2; ++fr) {
                    #pragma unroll
                    for (int i = 0; i < 4; ++i) {
                        int row = fr * 16 + g * 4 + i;
                        float rv = fsig(rr[fr][i] + brz);
                        float zv = fsig(zz[fr][i] + bzz2);
                        float ng = ftanh(ni[fr][i] + bin + rv * (nh[fr][i] + bhn));
                        float hp = bf2f(((unsigned short*)Atile)[((row * 32 + hc) ^ (row & 7)) * 8 + hel]);
                        float hv = ng + zv * (hp - ng);
                        hb[(size_t)(r0 + row) * 128 + c] = (unsigned short)f2bf(hv);
                    }
                }
            }
        }
    } else {
        // ================= lse1 + lse2 =================
        uint4* Alat = shbuf;            // 32x8
        uint4* Alt  = shbuf + 32 * 8;   // 32x16
        const int r0 = (blockIdx.x - NBLK_) * 32;

        if (tid < 256) {
            int row = tid >> 3, c = tid & 7;
            const float4* p = (const float4*)(latent + (size_t)(r0 + row) * 64 + c * 8);
            Alat[(row * 8 + c) ^ (row & 7)] = pack8(p[0], p[1]);
        }
        __syncthreads();

        // lse1: K=64, O=128; wave w: cols w*16 -> Alt
        {
            f32x4 acc[2] = {};
            #pragma unroll
            for (int ks = 0; ks < 2; ++ks) {
                bf16x8 bf = ldb_frag(w1b, w * 16 + m, 64, ks * 4 + g);
                #pragma unroll
                for (int fr = 0; fr < 2; ++fr) {
                    bf16x8 af = lda_frag(Alat, 8, fr * 16 + m, ks * 4 + g);
                    acc[fr] = __builtin_amdgcn_mfma_f32_16x16x32_bf16(af, bf, acc[fr], 0, 0, 0);
                }
            }
            int col = w * 16 + m;
            float bv = b1[col];
            int c = col >> 3, el = col & 7;
            #pragma unroll
            for (int fr = 0; fr < 2; ++fr) {
                #pragma unroll
                for (int i = 0; i < 4; ++i) {
                    int row = fr * 16 + g * 4 + i;
                    float v = acc[fr][i] + bv;
                    v = v > 0.f ? v : 0.f;
                    ((unsigned short*)Alt)[((row * 16 + c) ^ (row & 7)) * 8 + el] =
                        (unsigned short)f2bf(v);
                }
            }
        }
        __syncthreads();

        // lse2: K=128, O=128 -> leb
        {
            f32x4 acc[2] = {};
            #pragma unroll
            for (int ks = 0; ks < 4; ++ks) {
                bf16x8 bf = ldb_frag(w2b, w * 16 + m, 128, ks * 4 + g);
                #pragma unroll
                for (int fr = 0; fr < 2; ++fr) {
                    bf16x8 af = lda_frag(Alt, 16, fr * 16 + m, ks * 4 + g);
                    acc[fr] = __builtin_amdgcn_mfma_f32_16x16x32_bf16(af, bf, acc[fr], 0, 0, 0);
                }
            }
            int col = w * 16 + m;
            float bv = b2[col];
            #pragma unroll
            for (int fr = 0; fr < 2; ++fr) {
                #pragma unroll
                for (int i = 0; i < 4; ++i) {
                    int rowl = fr * 16 + g * 4 + i;
                    float v = acc[fr][i] + bv;
                    leb[(size_t)(r0 + rowl) * 128 + col] = (unsigned short)f2bf(v);
                }
            }
        }
    }
}

// ---------------------------------------------------------------------------
// me1 GEMM (K=256, O=256) + BN partial sums + fused hl projection, 32-row blocks.
__global__ __launch_bounds__(256, 4)
void me1_stats(const unsigned short* __restrict__ hb, const unsigned short* __restrict__ leb,
               const unsigned short* __restrict__ W, const float* __restrict__ bias,
               const unsigned short* __restrict__ f2w, const float* __restrict__ fc2_b,
               unsigned short* __restrict__ t1,
               float* __restrict__ psum, float* __restrict__ psq,
               float* __restrict__ hl)
{
    __shared__ uint4 Atile[32 * 32];
    __shared__ uint4 T1b[32 * 32];   // t1 bounce (linear 32x256 bf16)
    const int tid = threadIdx.x;
    const int r0 = blockIdx.x * 32;

    for (int idx = tid; idx < 32 * 16; idx += 256) {
        int row = idx >> 4, c = idx & 15;
        Atile[(row * 32 + c) ^ (row & 7)] =
            *(const uint4*)(hb + (size_t)(r0 + row) * 128 + c * 8);
        Atile[(row * 32 + (16 + c)) ^ (row & 7)] =
            *(const uint4*)(leb + (size_t)(r0 + row) * 128 + c * 8);
    }
    __syncthreads();

    const int lane = tid & 63, w = tid >> 6;
    const int m = lane & 15, g = lane >> 4;
    unsigned short* t1s = (unsigned short*)T1b;

    for (int ot = 0; ot < 2; ++ot) {
        const int o0 = ot * 128 + w * 32;
        f32x4 acc[2][2] = {};
        #pragma unroll
        for (int ks = 0; ks < 8; ++ks) {
            bf16x8 af[2], bf[2];
            #pragma unroll
            for (int fr = 0; fr < 2; ++fr)
                af[fr] = lda_frag(Atile, 32, fr * 16 + m, ks * 4 + g);
            #pragma unroll
            for (int fc = 0; fc < 2; ++fc)
                bf[fc] = ldb_frag(W, o0 + fc * 16 + m, 256, ks * 4 + g);
            #pragma unroll
            for (int fr = 0; fr < 2; ++fr)
                #pragma unroll
                for (int fc = 0; fc < 2; ++fc)
                    acc[fr][fc] = __builtin_amdgcn_mfma_f32_16x16x32_bf16(
                        af[fr], bf[fc], acc[fr][fc], 0, 0, 0);
        }
        #pragma unroll
        for (int fc = 0; fc < 2; ++fc) {
            int col = o0 + fc * 16 + m;
            float bv = bias[col];
            float s = 0.f, q = 0.f;
            #pragma unroll
            for (int fr = 0; fr < 2; ++fr) {
                #pragma unroll
                for (int i = 0; i < 4; ++i) {
                    int rowl = fr * 16 + g * 4 + i;
                    float v = acc[fr][fc][i] + bv;
                    t1s[rowl * 256 + col] = (unsigned short)f2bf(v);
                    s += v; q += v * v;
                }
            }
            s += __shfl_xor(s, 16); s += __shfl_xor(s, 32);  // over g (all 32 rows)
            q += __shfl_xor(q, 16); q += __shfl_xor(q, 32);
            if (lane < 16) {
                psum[(size_t)blockIdx.x * 256 + col] = s;
                psq[(size_t)blockIdx.x * 256 + col] = q;
            }
        }
    }
    __syncthreads();
    for (int idx = tid; idx < 32 * 32; idx += 256) {  // coalesced t1 store
        int row = idx >> 5, c = idx & 31;
        *(uint4*)(t1 + (size_t)(r0 + row) * 256 + c * 8) = T1b[row * 32 + c];
    }

    // ---- fused hl: waves 0-1 rows w*16..w*16+15, cols 0..29 ----
    if (w < 2) {
        f32x4 acc[2] = {};
        #pragma unroll
        for (int ks = 0; ks < 8; ++ks) {
            bf16x8 af = lda_frag(Atile, 32, w * 16 + m, ks * 4 + g);
            bf16x8 bf[2];
            #pragma unroll
            for (int fc = 0; fc < 2; ++fc) {
                int col = fc * 16 + m;
                bf[fc] = (col < NA_) ? ldb_frag(f2w, col, 1280, ks * 4 + g) : bf16x8{};
            }
            #pragma unroll
            for (int fc = 0; fc < 2; ++fc)
                acc[fc] = __builtin_amdgcn_mfma_f32_16x16x32_bf16(af, bf[fc], acc[fc], 0, 0, 0);
        }
        #pragma unroll
        for (int fc = 0; fc < 2; ++fc) {
            int col = fc * 16 + m;
            if (col < NA_) {
                float bv = fc2_b[col];
                #pragma unroll
                for (int i = 0; i < 4; ++i) {
                    int row = r0 + w * 16 + g * 4 + i;
                    hl[(size_t)row * NA_ + col] = acc[fc][i] + bv;
                }
            }
        }
    }
}

// ---------------------------------------------------------------------------
// Parallel BN finalize: one block per feature; threads stride over NBLK_.
__global__ __launch_bounds__(256)
void bn_final_kernel(const float* __restrict__ psum, const float* __restrict__ psq,
                     const float* __restrict__ g, const float* __restrict__ beta,
                     float* __restrict__ scale, float* __restrict__ shift)
{
    __shared__ float redS[4], redQ[4];
    const int f = blockIdx.x;
    const int tid = threadIdx.x;
    float s = 0.f, q = 0.f;
    for (int b = tid; b < NBLK_; b += 256) {
        s += psum[(size_t)b * 256 + f];
        q += psq[(size_t)b * 256 + f];
    }
    #pragma unroll
    for (int off = 32; off >= 1; off >>= 1) {
        s += __shfl_down(s, off);
        q += __shfl_down(q, off);
    }
    if ((tid & 63) == 0) { redS[tid >> 6] = s; redQ[tid >> 6] = q; }
    __syncthreads();
    if (tid == 0) {
        s = redS[0] + redS[1] + redS[2] + redS[3];
        q = redQ[0] + redQ[1] + redQ[2] + redQ[3];
        float mean = s / (float)R_;
        float var = q / (float)R_ - mean * mean;
        float istd = rsqrtf(var + 1e-5f);
        float sc = g[f] * istd;
        scale[f] = sc;
        shift[f] = beta[f] - mean * sc;
    }
}

// ---------------------------------------------------------------------------
// Fused me2 + kq_norm + v1 + v2 (pm never leaves LDS).
__global__ __launch_bounds__(256, 4)
void me2kqv(const unsigned short* __restrict__ t1,
            const float* __restrict__ scale, const float* __restrict__ shift,
            const unsigned short* __restrict__ W2, const float* __restrict__ me2_b,
            const float* __restrict__ eps,
            const unsigned short* __restrict__ hb,
            const unsigned short* __restrict__ kwb, const float* __restrict__ k_b,
            const unsigned short* __restrict__ qwb, const float* __restrict__ q_b,
            const unsigned short* __restrict__ v1w, const float* __restrict__ v1_b,
            const unsigned short* __restrict__ v2w, const float* __restrict__ v2_b,
            float* __restrict__ kh, float* __restrict__ qh,
            unsigned short* __restrict__ valb)
{
    __shared__ uint4 bufA[32 * 32];   // 16 KB: t1(BN) tile, then A3 (t3)
    __shared__ uint4 bufB[32 * 24];   // 12 KB: [h 0..15 | pm 16..23]; later val bounce
    __shared__ float sc_s[256], sh_s[256];
    const int tid = threadIdx.x;
    const int r0 = blockIdx.x * 32;

    sc_s[tid] = scale[tid];
    sh_s[tid] = shift[tid];
    for (int idx = tid; idx < 32 * 16; idx += 256) {
        int row = idx >> 4, c = idx & 15;
        bufB[(row * 24 + c) ^ (row & 7)] =
            *(const uint4*)(hb + (size_t)(r0 + row) * 128 + c * 8);
    }
    __syncthreads();

    // stage t1 with BN(scale/shift)+lrelu -> bufA (swizzled)
    for (int idx = tid; idx < 32 * 32; idx += 256) {
        int row = idx >> 5, c = idx & 31;
        uint4 u = *(const uint4*)(t1 + (size_t)(r0 + row) * 256 + c * 8);
        unsigned int vv[4] = {u.x, u.y, u.z, u.w};
        float f[8];
        #pragma unroll
        for (int q2 = 0; q2 < 4; ++q2) {
            f[2 * q2]     = __uint_as_float((vv[q2] & 0xffffu) << 16);
            f[2 * q2 + 1] = __uint_as_float(vv[q2] & 0xffff0000u);
        }
        int k = c * 8;
        #pragma unroll
        for (int j = 0; j < 8; ++j) {
            float v = f[j] * sc_s[k + j] + sh_s[k + j];
            f[j] = v > 0.f ? v : 0.01f * v;
        }
        uint4 r;
        r.x = pack2(f[0], f[1]); r.y = pack2(f[2], f[3]);
        r.z = pack2(f[4], f[5]); r.w = pack2(f[6], f[7]);
        bufA[(row * 32 + c) ^ (row & 7)] = r;
    }
    __syncthreads();

    const int lane = tid & 63, w = tid >> 6;
    const int m = lane & 15, g = lane >> 4;

    // ---- me2 GEMM: wave w owns mean col w*16+m (fc=0), std col 64+w*16+m ----
    {
        f32x4 acc[2][2] = {};
        #pragma unroll
        for (int ks = 0; ks < 8; ++ks) {
            bf16x8 af[2], bf[2];
            #pragma unroll
            for (int fr = 0; fr < 2; ++fr)
                af[fr] = lda_frag(bufA, 32, fr * 16 + m, ks * 4 + g);
            bf[0] = ldb_frag(W2, w * 16 + m, 256, ks * 4 + g);
            bf[1] = ldb_frag(W2, 64 + w * 16 + m, 256, ks * 4 + g);
            #pragma unroll
            for (int fr = 0; fr < 2; ++fr)
                #pragma unroll
                for (int fc = 0; fc < 2; ++fc)
                    acc[fr][fc] = __builtin_amdgcn_mfma_f32_16x16x32_bf16(
                        af[fr], bf[fc], acc[fr][fc], 0, 0, 0);
        }
        int cp = w * 16 + m;  // 0..63
        float bv0 = me2_b[cp], bv1 = me2_b[64 + cp];
        int hc = 16 + (cp >> 3), hel = cp & 7;
        #pragma unroll
        for (int fr = 0; fr < 2; ++fr) {
            #pragma unroll
            for (int i = 0; i < 4; ++i) {
                float vm = acc[fr][0][i] + bv0;
                vm = vm > 0.f ? vm : 0.01f * vm;
                vm = fminf(fmaxf(vm, -1.f), 1.f);
                float vs = acc[fr][1][i] + bv1;
                vs = vs > 0.f ? vs : 0.01f * vs;
                vs = fminf(fmaxf(vs, 0.5f), 1.f);
                int row = fr * 16 + g * 4 + i;
                float e = eps[(size_t)(r0 + row) * 64 + cp];
                ((unsigned short*)bufB)[((row * 24 + hc) ^ (row & 7)) * 8 + hel] =
                    (unsigned short)f2bf(vm + vs * e);
            }
        }
    }
    __syncthreads();   // pm visible in bufB; bufA (t1) dead

    // ---- phase 0: wave 0 -> kh, wave 1 -> qh ----
    if (w < 2) {
        const bool isq = (w == 1);
        f32x4 acc[2][2] = {};
        const int nks = isq ? 2 : 4;
        for (int ks = 0; ks < nks; ++ks) {
            bf16x8 af[2], bf[2];
            #pragma unroll
            for (int fr = 0; fr < 2; ++fr)
                af[fr] = lda_frag(bufB, 24, fr * 16 + m, (isq ? 16 : 0) + ks * 4 + g);
            #pragma unroll
            for (int fc = 0; fc < 2; ++fc)
                bf[fc] = isq ? ldb_frag(qwb, fc * 16 + m, 64, ks * 4 + g)
                             : ldb_frag(kwb, fc * 16 + m, 128, ks * 4 + g);
            #pragma unroll
            for (int fr = 0; fr < 2; ++fr)
                #pragma unroll
                for (int fc = 0; fc < 2; ++fc)
                    acc[fr][fc] = __builtin_amdgcn_mfma_f32_16x16x32_bf16(
                        af[fr], bf[fc], acc[fr][fc], 0, 0, 0);
        }
        const float* bias = isq ? q_b : k_b;
        float b0 = bias[m], b1 = bias[16 + m];
        float* outp = isq ? qh : kh;
        #pragma unroll
        for (int fr = 0; fr < 2; ++fr) {
            #pragma unroll
            for (int i = 0; i < 4; ++i) {
                float v0 = acc[fr][0][i] + b0;
                float v1 = acc[fr][1][i] + b1;
                float ss = v0 * v0 + v1 * v1;
                ss += __shfl_xor(ss, 1); ss += __shfl_xor(ss, 2);
                ss += __shfl_xor(ss, 4); ss += __shfl_xor(ss, 8);
                float inv = 1.f / fmaxf(sqrtf(ss), 1e-8f);
                int row = r0 + fr * 16 + g * 4 + i;
                outp[(size_t)row * 32 + m] = v0 * inv;
                outp[(size_t)row * 32 + 16 + m] = v1 * inv;
            }
        }
    }

    // ---- phase 1: v1 (K=192, O=256) -> bufA as A3 ----
    for (int ot = 0; ot < 2; ++ot) {
        const int o0 = ot * 128 + w * 32;
        f32x4 acc[2][2] = {};
        #pragma unroll
        for (int ks = 0; ks < 6; ++ks) {
            bf16x8 af[2], bf[2];
            #pragma unroll
            for (int fr = 0; fr < 2; ++fr)
                af[fr] = lda_frag(bufB, 24, fr * 16 + m, ks * 4 + g);
            #pragma unroll
            for (int fc = 0; fc < 2; ++fc)
                bf[fc] = ldb_frag(v1w, o0 + fc * 16 + m, 192, ks * 4 + g);
            #pragma unroll
            for (int fr = 0; fr < 2; ++fr)
                #pragma unroll
                for (int fc = 0; fc < 2; ++fc)
                    acc[fr][fc] = __builtin_amdgcn_mfma_f32_16x16x32_bf16(
                        af[fr], bf[fc], acc[fr][fc], 0, 0, 0);
        }
        #pragma unroll
        for (int fc = 0; fc < 2; ++fc) {
            int col = o0 + fc * 16 + m;
            float bv = v1_b[col];
            int c = col >> 3, el = col & 7;
            #pragma unroll
            for (int fr = 0; fr < 2; ++fr) {
                #pragma unroll
                for (int i = 0; i < 4; ++i) {
                    int row = fr * 16 + g * 4 + i;
                    float v = acc[fr][fc][i] + bv;
                    v = v > 0.f ? v : 0.01f * v;
                    ((unsigned short*)bufA)[((row * 32 + c) ^ (row & 7)) * 8 + el] =
                        (unsigned short)f2bf(v);
                }
            }
        }
    }
    __syncthreads();

    // ---- phase 2: v2 (K=256, O=64); wave w: cols w*16; bounce -> coalesced ----
    {
        f32x4 acc[2] = {};
        #pragma unroll
        for (int ks = 0; ks < 8; ++ks) {
            bf16x8 af[2];
            #pragma unroll
            for (int fr = 0; fr < 2; ++fr)
                af[fr] = lda_frag(bufA, 32, fr * 16 + m, ks * 4 + g);
            bf16x8 bf = ldb_frag(v2w, w * 16 + m, 256, ks * 4 + g);
            #pragma unroll
            for (int fr = 0; fr < 2; ++fr)
                acc[fr] = __builtin_amdgcn_mfma_f32_16x16x32_bf16(af[fr], bf, acc[fr], 0, 0, 0);
        }
        int col = w * 16 + m;
        float bv = v2_b[col];
        unsigned short* vb = (unsigned short*)bufB;  // bufB dead after v1
        #pragma unroll
        for (int fr = 0; fr < 2; ++fr) {
            #pragma unroll
            for (int i = 0; i < 4; ++i) {
                int rowl = fr * 16 + g * 4 + i;
                vb[rowl * 64 + col] = (unsigned short)f2bf(acc[fr][i] + bv);
            }
        }
    }
    __syncthreads();
    {   // 32x64 bf16 = 256 uint4: one per thread
        int row = tid >> 3, c = tid & 7;
        *(uint4*)(valb + (size_t)(r0 + row) * 64 + c * 8) = ((uint4*)bufB)[row * 8 + c];
    }
}

// ---------------------------------------------------------------------------
// vproj[r][na] = w2[na, 256+64*(r%16) .. +64] . value[r]   (value bf16, w2 f32)
__global__ __launch_bounds__(256)
void vproj_kernel(const unsigned short* __restrict__ value, const float* __restrict__ w2,
                  float* __restrict__ vproj)
{
    __shared__ float w2s[NA_][65];
    __shared__ float val_s[64][65];
    const int tid = threadIdx.x;
    const int j = blockIdx.x & 15;
    const int b0 = (blockIdx.x >> 4) * 64;

    for (int idx = tid; idx < NA_ * 64; idx += 256) {
        int na = idx >> 6, k = idx & 63;
        w2s[na][k] = w2[(size_t)na * 1280 + 256 + j * 64 + k];
    }
    for (int idx = tid; idx < 64 * 64; idx += 256) {
        int bl = idx >> 6, k = idx & 63;
        val_s[bl][k] = bf2f(value[((size_t)(b0 + bl) * 16 + j) * 64 + k]);
    }
    __syncthreads();

    for (int task = tid; task < 64 * NA_; task += 256) {
        int bl = task / NA_, na = task - bl * NA_;
        float acc = 0.f;
        #pragma unroll 16
        for (int k = 0; k < 64; ++k) acc = fmaf(val_s[bl][k], w2s[na][k], acc);
        vproj[((size_t)(b0 + bl) * 16 + j) * NA_ + na] = acc;
    }
}

// Per batch: cosine logits (16x16), softmax over j, zero diag, combine.
__global__ __launch_bounds__(256)
void attn_combine(const float* __restrict__ kh, const float* __restrict__ qh,
                  const float* __restrict__ vproj, const float* __restrict__ hl,
                  float* __restrict__ outv)
{
    __shared__ float kh_s[16][33], qh_s[16][33];
    __shared__ float al_s[16][16];
    __shared__ float vp_s[16][NA_];
    const int tid = threadIdx.x;
    const size_t rb = (size_t)blockIdx.x * 16;

    for (int idx = tid; idx < 512; idx += 256) {
        int r = idx >> 5, a = idx & 31;
        kh_s[r][a] = kh[rb * 32 + idx];
        qh_s[r][a] = qh[rb * 32 + idx];
    }
    for (int idx = tid; idx < 16 * NA_; idx += 256)
        vp_s[idx / NA_][idx % NA_] = vproj[rb * NA_ + idx];
    __syncthreads();

    {
        int i = tid >> 4, j = tid & 15;
        float l = 0.f;
        #pragma unroll
        for (int a = 0; a < 32; ++a) l = fmaf(kh_s[i][a], qh_s[j][a], l);
        float mx = l;
        #pragma unroll
        for (int mm = 8; mm >= 1; mm >>= 1) mx = fmaxf(mx, __shfl_xor(mx, mm));
        float e = __expf(l - mx);
        float s = e;
        #pragma unroll
        for (int mm = 8; mm >= 1; mm >>= 1) s += __shfl_xor(s, mm);
        float a = e / s;
        if (i == j) a = 0.f;
        al_s[i][j] = a;
    }
    __syncthreads();

    for (int task = tid; task < 16 * NA_; task += 256) {
        int i = task / NA_, na = task - i * NA_;
        float acc = hl[(rb + i) * NA_ + na];
        #pragma unroll
        for (int j = 0; j < 16; ++j) acc = fmaf(al_s[i][j], vp_s[j][na], acc);
        outv[(rb + i) * NA_ + na] = acc;
    }
}

extern "C" void kernel_launch(void* const* d_in, const int* in_sizes, int n_in,
                              void* d_out, int out_size, void* d_ws, size_t ws_size,
                              hipStream_t stream)
{
    (void)in_sizes; (void)n_in; (void)out_size; (void)ws_size;
    const float* inputs  = (const float*)d_in[0];
    const float* hidden  = (const float*)d_in[1];
    const float* latent  = (const float*)d_in[2];
    const float* eps     = (const float*)d_in[3];
    const float* fc1_w   = (const float*)d_in[4];
    const float* fc1_b   = (const float*)d_in[5];
    const float* w_ih    = (const float*)d_in[6];
    const float* w_hh    = (const float*)d_in[7];
    const float* b_ih    = (const float*)d_in[8];
    const float* b_hh    = (const float*)d_in[9];
    const float* lse_w1  = (const float*)d_in[10];
    const float* lse_b1  = (const float*)d_in[11];
    const float* lse_w2  = (const float*)d_in[12];
    const float* lse_b2  = (const float*)d_in[13];
    const float* me_w1   = (const float*)d_in[14];
    const float* me_b1   = (const float*)d_in[15];
    const float* me_g    = (const float*)d_in[16];
    const float* me_beta = (const float*)d_in[17];
    const float* me_w2   = (const float*)d_in[18];
    const float* me_b2   = (const float*)d_in[19];
    const float* k_w     = (const float*)d_in[20];
    const float* k_b     = (const float*)d_in[21];
    const float* q_w     = (const float*)d_in[22];
    const float* q_b     = (const float*)d_in[23];
    const float* v_w1    = (const float*)d_in[24];
    const float* v_b1    = (const float*)d_in[25];
    const float* v_w2    = (const float*)d_in[26];
    const float* v_b2    = (const float*)d_in[27];
    const float* fc2_w   = (const float*)d_in[28];
    const float* fc2_b   = (const float*)d_in[29];

    const size_t R = R_;
    // Workspace layout: bf16 activations, bf16 weights, then f32 buffers.
    unsigned short* bws = (unsigned short*)d_ws;
    unsigned short* hb   = bws;               // R*128
    unsigned short* leb  = hb + R * 128;      // R*128
    unsigned short* t1b  = leb + R * 128;     // R*256
    unsigned short* valb = t1b + R * 256;     // R*64
    unsigned short* wb   = valb + R * 64;     // 347648 (bf16 weights)
    float* fws  = (float*)(wb + woff::total);
    float* khf  = fws;                 // R*32
    float* qhf  = khf + R * 32;        // R*32
    float* hlf  = qhf + R * 32;        // R*30
    float* vpf  = hlf + R * 30;        // R*30
    float* psum = vpf + R * 30;        // NBLK_*256
    float* psq  = psum + (size_t)NBLK_ * 256;
    float* scale = psq + (size_t)NBLK_ * 256;
    float* shift = scale + 256;

    dim3 blk(256);
    dim3 g1024(NBLK_);

    // 0) weights -> bf16 (once per call; cheap)
    wcvt_kernel<<<dim3((woff::total + 255) / 256), blk, 0, stream>>>(
        fc1_w, w_ih, w_hh, lse_w1, lse_w2, me_w1, me_w2, k_w, q_w, v_w1, v_w2, fc2_w, wb);

    // 1) merged stage1 (512 threads, 8 waves, (512,6): 84-reg cap, no spill):
    //    fc1+GRU (blocks 0..1023), lse1+lse2 (blocks 1024..2047)
    stage1<<<dim3(2 * NBLK_), dim3(512), 0, stream>>>(
        inputs, hidden, wb + woff::fc1, fc1_b, wb + woff::ih, wb + woff::hh,
        b_ih, b_hh, hb,
        latent, wb + woff::l1, lse_b1, wb + woff::l2, lse_b2, leb);
    // 2) t1 = me1(cat(h,le)) -> bf16 + BN partial stats + hl projection
    me1_stats<<<g1024, blk, 0, stream>>>(hb, leb, wb + woff::m1, me_b1,
                                         wb + woff::f2, fc2_b, t1b, psum, psq, hlf);
    // 2b) BN finalize (parallel: one block per feature)
    bn_final_kernel<<<dim3(256), blk, 0, stream>>>(psum, psq, me_g, me_beta, scale, shift);
    // 3) fused me2(BN(t1)) -> pm [LDS] -> kq_norm + v1 + v2 -> kh/qh/value
    me2kqv<<<g1024, blk, 0, stream>>>(t1b, scale, shift, wb + woff::m2, me_b2, eps,
                                      hb, wb + woff::kw, k_b, wb + woff::qw, q_b,
                                      wb + woff::v1, v_b1, wb + woff::v2, v_b2,
                                      khf, qhf, valb);
    // 4) vproj = per-agent fc2_w slice . value
    vproj_kernel<<<dim3(16 * (BSB_ / 64)), blk, 0, stream>>>(valb, fc2_w, vpf);
    // 5) softmax + combine -> out
    attn_combine<<<dim3(BSB_), blk, 0, stream>>>(khf, qhf, vpf, hlf, (float*)d_out);
}

// Round 16
// 125.468 us; speedup vs baseline: 1.2244x; 1.0976x over previous
//
#include <hip/hip_runtime.h>
#include <math.h>

// Problem constants (fixed instance)
namespace {
constexpr int R_ = 32768;     // BS*N rows
constexpr int N_ = 16;
constexpr int NA_ = 30;
constexpr int BSB_ = R_ / N_; // 2048 batches
constexpr int NBLK_ = R_ / 32; // 1024 row-blocks (32 rows each)
constexpr int NB64_ = R_ / 64; // 512 row-blocks (64 rows each, stage1)
}

typedef __bf16 bf16x8 __attribute__((ext_vector_type(8)));
typedef float f32x4 __attribute__((ext_vector_type(4)));

__device__ inline unsigned int f2bf(float f) {
    unsigned int u = __float_as_uint(f);
    return (u + 0x7fffu + ((u >> 16) & 1u)) >> 16;  // RTN-even
}
__device__ inline float bf2f(unsigned int us) {
    return __uint_as_float(us << 16);
}
__device__ inline unsigned int pack2(float a, float b) {
    return f2bf(a) | (f2bf(b) << 16);
}
__device__ inline uint4 pack8(float4 f0, float4 f1) {
    uint4 u;
    u.x = pack2(f0.x, f0.y); u.y = pack2(f0.z, f0.w);
    u.z = pack2(f1.x, f1.y); u.w = pack2(f1.z, f1.w);
    return u;
}
// Fast transcendentals (v_exp/v_rcp); rel err ~2^-21 << bf16 rounding 2^-9.
__device__ inline float fsig(float x)  { return __builtin_amdgcn_rcpf(1.f + __expf(-x)); }
__device__ inline float ftanh(float x) { return 1.f - 2.f * __builtin_amdgcn_rcpf(__expf(2.f * x) + 1.f); }

// A fragment from swizzled LDS tile (KC = 16B-chunks per row)
__device__ __forceinline__ bf16x8 lda_frag(const uint4* At, int KC, int row, int c) {
    return __builtin_bit_cast(bf16x8, At[(row * KC + c) ^ (row & 7)]);
}
// B fragment direct from global bf16 weights
__device__ __forceinline__ bf16x8 ldb_frag(const unsigned short* W, int row, int rstride, int c) {
    return __builtin_bit_cast(bf16x8, *(const uint4*)(W + (size_t)row * rstride + (size_t)c * 8));
}

// ---------------------------------------------------------------------------
// One-shot weight conversion f32 -> bf16 into workspace (concatenated).
namespace woff {
constexpr unsigned fc1 = 0;
constexpr unsigned ih  = 16384;
constexpr unsigned hh  = 65536;
constexpr unsigned l1  = 114688;
constexpr unsigned l2  = 122880;
constexpr unsigned m1  = 139264;
constexpr unsigned m2  = 204800;
constexpr unsigned kw  = 237568;
constexpr unsigned qw  = 241664;
constexpr unsigned v1  = 243712;
constexpr unsigned v2  = 292864;
constexpr unsigned f2  = 309248;
constexpr unsigned total = 347648;
}

__global__ __launch_bounds__(256)
void wcvt_kernel(const float* __restrict__ fc1_w, const float* __restrict__ w_ih,
                 const float* __restrict__ w_hh, const float* __restrict__ lse_w1,
                 const float* __restrict__ lse_w2, const float* __restrict__ me_w1,
                 const float* __restrict__ me_w2, const float* __restrict__ k_w,
                 const float* __restrict__ q_w, const float* __restrict__ v_w1,
                 const float* __restrict__ v_w2, const float* __restrict__ fc2_w,
                 unsigned short* __restrict__ dst)
{
    unsigned i = blockIdx.x * 256 + threadIdx.x;
    if (i >= woff::total) return;
    const float* src; unsigned base;
    if      (i < woff::ih) { src = fc1_w;  base = woff::fc1; }
    else if (i < woff::hh) { src = w_ih;   base = woff::ih; }
    else if (i < woff::l1) { src = w_hh;   base = woff::hh; }
    else if (i < woff::l2) { src = lse_w1; base = woff::l1; }
    else if (i < woff::m1) { src = lse_w2; base = woff::l2; }
    else if (i < woff::m2) { src = me_w1;  base = woff::m1; }
    else if (i < woff::kw) { src = me_w2;  base = woff::m2; }
    else if (i < woff::qw) { src = k_w;    base = woff::kw; }
    else if (i < woff::v1) { src = q_w;    base = woff::qw; }
    else if (i < woff::v2) { src = v_w1;   base = woff::v1; }
    else if (i < woff::f2) { src = v_w2;   base = woff::v2; }
    else                   { src = fc2_w;  base = woff::f2; }
    dst[i] = (unsigned short)f2bf(src[i - base]);
}

// ---------------------------------------------------------------------------
// Merged stage 1, 64-row tiles, 512 threads / 8 waves, wave w: 16-col strip
// with 4 row-fragments (B-frag reuse x4). (512,4): 128-reg cap fits the
// ~110-reg GRU wave (64 AGPR acc) without spill ((512,6)'s 84-cap would spill).
// Blocks [0,512): fc1+GRU. Blocks [512,1024): lse1+lse2.
__global__ __launch_bounds__(512, 4)
void stage1(const float* __restrict__ inputs, const float* __restrict__ hidden,
            const unsigned short* __restrict__ fc1w, const float* __restrict__ fc1_b,
            const unsigned short* __restrict__ wih, const unsigned short* __restrict__ whh,
            const float* __restrict__ b_ih, const float* __restrict__ b_hh,
            unsigned short* __restrict__ hb,
            const float* __restrict__ latent,
            const unsigned short* __restrict__ w1b, const float* __restrict__ b1,
            const unsigned short* __restrict__ w2b, const float* __restrict__ b2,
            unsigned short* __restrict__ leb)
{
    __shared__ uint4 shbuf[64 * 48];   // 48 KB, unioned between both paths
    const int tid = threadIdx.x;
    const int lane = tid & 63, w = tid >> 6;      // w: 0..7
    const int m = lane & 15, g = lane >> 4;

    if (blockIdx.x < (unsigned)NB64_) {
        // ================= fc1 + GRU =================
        uint4* Ain   = shbuf;            // 64x16: inputs bf16
        uint4* Atile = shbuf + 64 * 16;  // 64x32: [x | hidden] bf16
        const int r0 = blockIdx.x * 64;

        for (int idx = tid; idx < 64 * 16; idx += 512) {
            int row = idx >> 4, c = idx & 15;
            const float4* p = (const float4*)(inputs + (size_t)(r0 + row) * 128 + c * 8);
            Ain[(row * 16 + c) ^ (row & 7)] = pack8(p[0], p[1]);
            const float4* ph = (const float4*)(hidden + (size_t)(r0 + row) * 128 + c * 8);
            Atile[(row * 32 + (16 + c)) ^ (row & 7)] = pack8(ph[0], ph[1]);
        }
        __syncthreads();

        // ---- phase 1: x = relu(fc1); wave w: cols w*16..w*16+15, 64 rows ----
        {
            f32x4 acc[4] = {};
            #pragma unroll
            for (int ks = 0; ks < 4; ++ks) {
                bf16x8 bf = ldb_frag(fc1w, w * 16 + m, 128, ks * 4 + g);
                #pragma unroll
                for (int fr = 0; fr < 4; ++fr) {
                    bf16x8 af = lda_frag(Ain, 16, fr * 16 + m, ks * 4 + g);
                    acc[fr] = __builtin_amdgcn_mfma_f32_16x16x32_bf16(af, bf, acc[fr], 0, 0, 0);
                }
            }
            int col = w * 16 + m;
            float bv = fc1_b[col];
            int c = col >> 3, el = col & 7;
            #pragma unroll
            for (int fr = 0; fr < 4; ++fr) {
                #pragma unroll
                for (int i = 0; i < 4; ++i) {
                    int row = fr * 16 + g * 4 + i;
                    float v = acc[fr][i] + bv;
                    v = v > 0.f ? v : 0.f;
                    ((unsigned short*)Atile)[((row * 32 + c) ^ (row & 7)) * 8 + el] =
                        (unsigned short)f2bf(v);
                }
            }
        }
        __syncthreads();

        // ---- phase 2: GRU; wave w: gate cols w*16..w*16+15, 64 rows ----
        {
            f32x4 rr[4] = {}, zz[4] = {}, ni[4] = {}, nh[4] = {};
            const int ro = w * 16 + m;
            #pragma unroll
            for (int ks = 0; ks < 4; ++ks) {  // x part: wih
                bf16x8 brr = ldb_frag(wih, ro, 128, ks * 4 + g);
                bf16x8 bzz = ldb_frag(wih, 128 + ro, 128, ks * 4 + g);
                bf16x8 bnn = ldb_frag(wih, 256 + ro, 128, ks * 4 + g);
                #pragma unroll
                for (int fr = 0; fr < 4; ++fr) {
                    bf16x8 af = lda_frag(Atile, 32, fr * 16 + m, ks * 4 + g);
                    rr[fr] = __builtin_amdgcn_mfma_f32_16x16x32_bf16(af, brr, rr[fr], 0, 0, 0);
                    zz[fr] = __builtin_amdgcn_mfma_f32_16x16x32_bf16(af, bzz, zz[fr], 0, 0, 0);
                    ni[fr] = __builtin_amdgcn_mfma_f32_16x16x32_bf16(af, bnn, ni[fr], 0, 0, 0);
                }
            }
            #pragma unroll
            for (int ks = 0; ks < 4; ++ks) {  // hidden part: whh
                bf16x8 brr = ldb_frag(whh, ro, 128, ks * 4 + g);
                bf16x8 bzz = ldb_frag(whh, 128 + ro, 128, ks * 4 + g);
                bf16x8 bnn = ldb_frag(whh, 256 + ro, 128, ks * 4 + g);
                #pragma unroll
                for (int fr = 0; fr < 4; ++fr) {
                    bf16x8 af = lda_frag(Atile, 32, fr * 16 + m, 16 + ks * 4 + g);
                    rr[fr] = __builtin_amdgcn_mfma_f32_16x16x32_bf16(af, brr, rr[fr], 0, 0, 0);
                    zz[fr] = __builtin_amdgcn_mfma_f32_16x16x32_bf16(af, bzz, zz[fr], 0, 0, 0);
                    nh[fr] = __builtin_amdgcn_mfma_f32_16x16x32_bf16(af, bnn, nh[fr], 0, 0, 0);
                }
            }
            {
                int c = ro;   // 0..127
                float brz = b_ih[c] + b_hh[c];
                float bzz2 = b_ih[128 + c] + b_hh[128 + c];
                float bin = b_ih[256 + c], bhn = b_hh[256 + c];
                int hc = 16 + (c >> 3), hel = c & 7;  // hidden chunk in Atile
                #pragma unroll
                for (int fr = 0; fr < 4; ++fr) {
                    #pragma unroll
                    for (int i = 0; i < 4; ++i) {
                        int row = fr * 16 + g * 4 + i;
                        float rv = fsig(rr[fr][i] + brz);
                        float zv = fsig(zz[fr][i] + bzz2);
                        float ng = ftanh(ni[fr][i] + bin + rv * (nh[fr][i] + bhn));
                        float hp = bf2f(((unsigned short*)Atile)[((row * 32 + hc) ^ (row & 7)) * 8 + hel]);
                        float hv = ng + zv * (hp - ng);
                        hb[(size_t)(r0 + row) * 128 + c] = (unsigned short)f2bf(hv);
                    }
                }
            }
        }
    } else {
        // ================= lse1 + lse2 =================
        uint4* Alat = shbuf;            // 64x8
        uint4* Alt  = shbuf + 64 * 8;   // 64x16
        const int r0 = (blockIdx.x - NB64_) * 64;

        {   // 512 items, one per thread
            int row = tid >> 3, c = tid & 7;
            const float4* p = (const float4*)(latent + (size_t)(r0 + row) * 64 + c * 8);
            Alat[(row * 8 + c) ^ (row & 7)] = pack8(p[0], p[1]);
        }
        __syncthreads();

        // lse1: K=64, O=128; wave w: cols w*16 -> Alt
        {
            f32x4 acc[4] = {};
            #pragma unroll
            for (int ks = 0; ks < 2; ++ks) {
                bf16x8 bf = ldb_frag(w1b, w * 16 + m, 64, ks * 4 + g);
                #pragma unroll
                for (int fr = 0; fr < 4; ++fr) {
                    bf16x8 af = lda_frag(Alat, 8, fr * 16 + m, ks * 4 + g);
                    acc[fr] = __builtin_amdgcn_mfma_f32_16x16x32_bf16(af, bf, acc[fr], 0, 0, 0);
                }
            }
            int col = w * 16 + m;
            float bv = b1[col];
            int c = col >> 3, el = col & 7;
            #pragma unroll
            for (int fr = 0; fr < 4; ++fr) {
                #pragma unroll
                for (int i = 0; i < 4; ++i) {
                    int row = fr * 16 + g * 4 + i;
                    float v = acc[fr][i] + bv;
                    v = v > 0.f ? v : 0.f;
                    ((unsigned short*)Alt)[((row * 16 + c) ^ (row & 7)) * 8 + el] =
                        (unsigned short)f2bf(v);
                }
            }
        }
        __syncthreads();

        // lse2: K=128, O=128 -> leb
        {
            f32x4 acc[4] = {};
            #pragma unroll
            for (int ks = 0; ks < 4; ++ks) {
                bf16x8 bf = ldb_frag(w2b, w * 16 + m, 128, ks * 4 + g);
                #pragma unroll
                for (int fr = 0; fr < 4; ++fr) {
                    bf16x8 af = lda_frag(Alt, 16, fr * 16 + m, ks * 4 + g);
                    acc[fr] = __builtin_amdgcn_mfma_f32_16x16x32_bf16(af, bf, acc[fr], 0, 0, 0);
                }
            }
            int col = w * 16 + m;
            float bv = b2[col];
            #pragma unroll
            for (int fr = 0; fr < 4; ++fr) {
                #pragma unroll
                for (int i = 0; i < 4; ++i) {
                    int rowl = fr * 16 + g * 4 + i;
                    float v = acc[fr][i] + bv;
                    leb[(size_t)(r0 + rowl) * 128 + col] = (unsigned short)f2bf(v);
                }
            }
        }
    }
}

// ---------------------------------------------------------------------------
// me1 GEMM (K=256, O=256) + BN partial sums + fused hl projection, 32-row blocks.
__global__ __launch_bounds__(256, 4)
void me1_stats(const unsigned short* __restrict__ hb, const unsigned short* __restrict__ leb,
               const unsigned short* __restrict__ W, const float* __restrict__ bias,
               const unsigned short* __restrict__ f2w, const float* __restrict__ fc2_b,
               unsigned short* __restrict__ t1,
               float* __restrict__ psum, float* __restrict__ psq,
               float* __restrict__ hl)
{
    __shared__ uint4 Atile[32 * 32];
    __shared__ uint4 T1b[32 * 32];   // t1 bounce (linear 32x256 bf16)
    const int tid = threadIdx.x;
    const int r0 = blockIdx.x * 32;

    for (int idx = tid; idx < 32 * 16; idx += 256) {
        int row = idx >> 4, c = idx & 15;
        Atile[(row * 32 + c) ^ (row & 7)] =
            *(const uint4*)(hb + (size_t)(r0 + row) * 128 + c * 8);
        Atile[(row * 32 + (16 + c)) ^ (row & 7)] =
            *(const uint4*)(leb + (size_t)(r0 + row) * 128 + c * 8);
    }
    __syncthreads();

    const int lane = tid & 63, w = tid >> 6;
    const int m = lane & 15, g = lane >> 4;
    unsigned short* t1s = (unsigned short*)T1b;

    for (int ot = 0; ot < 2; ++ot) {
        const int o0 = ot * 128 + w * 32;
        f32x4 acc[2][2] = {};
        #pragma unroll
        for (int ks = 0; ks < 8; ++ks) {
            bf16x8 af[2], bf[2];
            #pragma unroll
            for (int fr = 0; fr < 2; ++fr)
                af[fr] = lda_frag(Atile, 32, fr * 16 + m, ks * 4 + g);
            #pragma unroll
            for (int fc = 0; fc < 2; ++fc)
                bf[fc] = ldb_frag(W, o0 + fc * 16 + m, 256, ks * 4 + g);
            #pragma unroll
            for (int fr = 0; fr < 2; ++fr)
                #pragma unroll
                for (int fc = 0; fc < 2; ++fc)
                    acc[fr][fc] = __builtin_amdgcn_mfma_f32_16x16x32_bf16(
                        af[fr], bf[fc], acc[fr][fc], 0, 0, 0);
        }
        #pragma unroll
        for (int fc = 0; fc < 2; ++fc) {
            int col = o0 + fc * 16 + m;
            float bv = bias[col];
            float s = 0.f, q = 0.f;
            #pragma unroll
            for (int fr = 0; fr < 2; ++fr) {
                #pragma unroll
                for (int i = 0; i < 4; ++i) {
                    int rowl = fr * 16 + g * 4 + i;
                    float v = acc[fr][fc][i] + bv;
                    t1s[rowl * 256 + col] = (unsigned short)f2bf(v);
                    s += v; q += v * v;
                }
            }
            s += __shfl_xor(s, 16); s += __shfl_xor(s, 32);  // over g (all 32 rows)
            q += __shfl_xor(q, 16); q += __shfl_xor(q, 32);
            if (lane < 16) {
                psum[(size_t)blockIdx.x * 256 + col] = s;
                psq[(size_t)blockIdx.x * 256 + col] = q;
            }
        }
    }
    __syncthreads();
    for (int idx = tid; idx < 32 * 32; idx += 256) {  // coalesced t1 store
        int row = idx >> 5, c = idx & 31;
        *(uint4*)(t1 + (size_t)(r0 + row) * 256 + c * 8) = T1b[row * 32 + c];
    }

    // ---- fused hl: waves 0-1 rows w*16..w*16+15, cols 0..29 ----
    if (w < 2) {
        f32x4 acc[2] = {};
        #pragma unroll
        for (int ks = 0; ks < 8; ++ks) {
            bf16x8 af = lda_frag(Atile, 32, w * 16 + m, ks * 4 + g);
            bf16x8 bf[2];
            #pragma unroll
            for (int fc = 0; fc < 2; ++fc) {
                int col = fc * 16 + m;
                bf[fc] = (col < NA_) ? ldb_frag(f2w, col, 1280, ks * 4 + g) : bf16x8{};
            }
            #pragma unroll
            for (int fc = 0; fc < 2; ++fc)
                acc[fc] = __builtin_amdgcn_mfma_f32_16x16x32_bf16(af, bf[fc], acc[fc], 0, 0, 0);
        }
        #pragma unroll
        for (int fc = 0; fc < 2; ++fc) {
            int col = fc * 16 + m;
            if (col < NA_) {
                float bv = fc2_b[col];
                #pragma unroll
                for (int i = 0; i < 4; ++i) {
                    int row = r0 + w * 16 + g * 4 + i;
                    hl[(size_t)row * NA_ + col] = acc[fc][i] + bv;
                }
            }
        }
    }
}

// ---------------------------------------------------------------------------
// Parallel BN finalize: one block per feature; threads stride over NBLK_.
__global__ __launch_bounds__(256)
void bn_final_kernel(const float* __restrict__ psum, const float* __restrict__ psq,
                     const float* __restrict__ g, const float* __restrict__ beta,
                     float* __restrict__ scale, float* __restrict__ shift)
{
    __shared__ float redS[4], redQ[4];
    const int f = blockIdx.x;
    const int tid = threadIdx.x;
    float s = 0.f, q = 0.f;
    for (int b = tid; b < NBLK_; b += 256) {
        s += psum[(size_t)b * 256 + f];
        q += psq[(size_t)b * 256 + f];
    }
    #pragma unroll
    for (int off = 32; off >= 1; off >>= 1) {
        s += __shfl_down(s, off);
        q += __shfl_down(q, off);
    }
    if ((tid & 63) == 0) { redS[tid >> 6] = s; redQ[tid >> 6] = q; }
    __syncthreads();
    if (tid == 0) {
        s = redS[0] + redS[1] + redS[2] + redS[3];
        q = redQ[0] + redQ[1] + redQ[2] + redQ[3];
        float mean = s / (float)R_;
        float var = q / (float)R_ - mean * mean;
        float istd = rsqrtf(var + 1e-5f);
        float sc = g[f] * istd;
        scale[f] = sc;
        shift[f] = beta[f] - mean * sc;
    }
}

// ---------------------------------------------------------------------------
// Fused me2 + kq_norm + v1 + v2 (pm never leaves LDS).
__global__ __launch_bounds__(256, 4)
void me2kqv(const unsigned short* __restrict__ t1,
            const float* __restrict__ scale, const float* __restrict__ shift,
            const unsigned short* __restrict__ W2, const float* __restrict__ me2_b,
            const float* __restrict__ eps,
            const unsigned short* __restrict__ hb,
            const unsigned short* __restrict__ kwb, const float* __restrict__ k_b,
            const unsigned short* __restrict__ qwb, const float* __restrict__ q_b,
            const unsigned short* __restrict__ v1w, const float* __restrict__ v1_b,
            const unsigned short* __restrict__ v2w, const float* __restrict__ v2_b,
            float* __restrict__ kh, float* __restrict__ qh,
            unsigned short* __restrict__ valb)
{
    __shared__ uint4 bufA[32 * 32];   // 16 KB: t1(BN) tile, then A3 (t3)
    __shared__ uint4 bufB[32 * 24];   // 12 KB: [h 0..15 | pm 16..23]; later val bounce
    __shared__ float sc_s[256], sh_s[256];
    const int tid = threadIdx.x;
    const int r0 = blockIdx.x * 32;

    sc_s[tid] = scale[tid];
    sh_s[tid] = shift[tid];
    for (int idx = tid; idx < 32 * 16; idx += 256) {
        int row = idx >> 4, c = idx & 15;
        bufB[(row * 24 + c) ^ (row & 7)] =
            *(const uint4*)(hb + (size_t)(r0 + row) * 128 + c * 8);
    }
    __syncthreads();

    // stage t1 with BN(scale/shift)+lrelu -> bufA (swizzled)
    for (int idx = tid; idx < 32 * 32; idx += 256) {
        int row = idx >> 5, c = idx & 31;
        uint4 u = *(const uint4*)(t1 + (size_t)(r0 + row) * 256 + c * 8);
        unsigned int vv[4] = {u.x, u.y, u.z, u.w};
        float f[8];
        #pragma unroll
        for (int q2 = 0; q2 < 4; ++q2) {
            f[2 * q2]     = __uint_as_float((vv[q2] & 0xffffu) << 16);
            f[2 * q2 + 1] = __uint_as_float(vv[q2] & 0xffff0000u);
        }
        int k = c * 8;
        #pragma unroll
        for (int j = 0; j < 8; ++j) {
            float v = f[j] * sc_s[k + j] + sh_s[k + j];
            f[j] = v > 0.f ? v : 0.01f * v;
        }
        uint4 r;
        r.x = pack2(f[0], f[1]); r.y = pack2(f[2], f[3]);
        r.z = pack2(f[4], f[5]); r.w = pack2(f[6], f[7]);
        bufA[(row * 32 + c) ^ (row & 7)] = r;
    }
    __syncthreads();

    const int lane = tid & 63, w = tid >> 6;
    const int m = lane & 15, g = lane >> 4;

    // ---- me2 GEMM: wave w owns mean col w*16+m (fc=0), std col 64+w*16+m ----
    {
        f32x4 acc[2][2] = {};
        #pragma unroll
        for (int ks = 0; ks < 8; ++ks) {
            bf16x8 af[2], bf[2];
            #pragma unroll
            for (int fr = 0; fr < 2; ++fr)
                af[fr] = lda_frag(bufA, 32, fr * 16 + m, ks * 4 + g);
            bf[0] = ldb_frag(W2, w * 16 + m, 256, ks * 4 + g);
            bf[1] = ldb_frag(W2, 64 + w * 16 + m, 256, ks * 4 + g);
            #pragma unroll
            for (int fr = 0; fr < 2; ++fr)
                #pragma unroll
                for (int fc = 0; fc < 2; ++fc)
                    acc[fr][fc] = __builtin_amdgcn_mfma_f32_16x16x32_bf16(
                        af[fr], bf[fc], acc[fr][fc], 0, 0, 0);
        }
        int cp = w * 16 + m;  // 0..63
        float bv0 = me2_b[cp], bv1 = me2_b[64 + cp];
        int hc = 16 + (cp >> 3), hel = cp & 7;
        #pragma unroll
        for (int fr = 0; fr < 2; ++fr) {
            #pragma unroll
            for (int i = 0; i < 4; ++i) {
                float vm = acc[fr][0][i] + bv0;
                vm = vm > 0.f ? vm : 0.01f * vm;
                vm = fminf(fmaxf(vm, -1.f), 1.f);
                float vs = acc[fr][1][i] + bv1;
                vs = vs > 0.f ? vs : 0.01f * vs;
                vs = fminf(fmaxf(vs, 0.5f), 1.f);
                int row = fr * 16 + g * 4 + i;
                float e = eps[(size_t)(r0 + row) * 64 + cp];
                ((unsigned short*)bufB)[((row * 24 + hc) ^ (row & 7)) * 8 + hel] =
                    (unsigned short)f2bf(vm + vs * e);
            }
        }
    }
    __syncthreads();   // pm visible in bufB; bufA (t1) dead

    // ---- phase 0: wave 0 -> kh, wave 1 -> qh ----
    if (w < 2) {
        const bool isq = (w == 1);
        f32x4 acc[2][2] = {};
        const int nks = isq ? 2 : 4;
        for (int ks = 0; ks < nks; ++ks) {
            bf16x8 af[2], bf[2];
            #pragma unroll
            for (int fr = 0; fr < 2; ++fr)
                af[fr] = lda_frag(bufB, 24, fr * 16 + m, (isq ? 16 : 0) + ks * 4 + g);
            #pragma unroll
            for (int fc = 0; fc < 2; ++fc)
                bf[fc] = isq ? ldb_frag(qwb, fc * 16 + m, 64, ks * 4 + g)
                             : ldb_frag(kwb, fc * 16 + m, 128, ks * 4 + g);
            #pragma unroll
            for (int fr = 0; fr < 2; ++fr)
                #pragma unroll
                for (int fc = 0; fc < 2; ++fc)
                    acc[fr][fc] = __builtin_amdgcn_mfma_f32_16x16x32_bf16(
                        af[fr], bf[fc], acc[fr][fc], 0, 0, 0);
        }
        const float* bias = isq ? q_b : k_b;
        float b0 = bias[m], b1 = bias[16 + m];
        float* outp = isq ? qh : kh;
        #pragma unroll
        for (int fr = 0; fr < 2; ++fr) {
            #pragma unroll
            for (int i = 0; i < 4; ++i) {
                float v0 = acc[fr][0][i] + b0;
                float v1 = acc[fr][1][i] + b1;
                float ss = v0 * v0 + v1 * v1;
                ss += __shfl_xor(ss, 1); ss += __shfl_xor(ss, 2);
                ss += __shfl_xor(ss, 4); ss += __shfl_xor(ss, 8);
                float inv = 1.f / fmaxf(sqrtf(ss), 1e-8f);
                int row = r0 + fr * 16 + g * 4 + i;
                outp[(size_t)row * 32 + m] = v0 * inv;
                outp[(size_t)row * 32 + 16 + m] = v1 * inv;
            }
        }
    }

    // ---- phase 1: v1 (K=192, O=256) -> bufA as A3 ----
    for (int ot = 0; ot < 2; ++ot) {
        const int o0 = ot * 128 + w * 32;
        f32x4 acc[2][2] = {};
        #pragma unroll
        for (int ks = 0; ks < 6; ++ks) {
            bf16x8 af[2], bf[2];
            #pragma unroll
            for (int fr = 0; fr < 2; ++fr)
                af[fr] = lda_frag(bufB, 24, fr * 16 + m, ks * 4 + g);
            #pragma unroll
            for (int fc = 0; fc < 2; ++fc)
                bf[fc] = ldb_frag(v1w, o0 + fc * 16 + m, 192, ks * 4 + g);
            #pragma unroll
            for (int fr = 0; fr < 2; ++fr)
                #pragma unroll
                for (int fc = 0; fc < 2; ++fc)
                    acc[fr][fc] = __builtin_amdgcn_mfma_f32_16x16x32_bf16(
                        af[fr], bf[fc], acc[fr][fc], 0, 0, 0);
        }
        #pragma unroll
        for (int fc = 0; fc < 2; ++fc) {
            int col = o0 + fc * 16 + m;
            float bv = v1_b[col];
            int c = col >> 3, el = col & 7;
            #pragma unroll
            for (int fr = 0; fr < 2; ++fr) {
                #pragma unroll
                for (int i = 0; i < 4; ++i) {
                    int row = fr * 16 + g * 4 + i;
                    float v = acc[fr][fc][i] + bv;
                    v = v > 0.f ? v : 0.01f * v;
                    ((unsigned short*)bufA)[((row * 32 + c) ^ (row & 7)) * 8 + el] =
                        (unsigned short)f2bf(v);
                }
            }
        }
    }
    __syncthreads();

    // ---- phase 2: v2 (K=256, O=64); wave w: cols w*16; bounce -> coalesced ----
    {
        f32x4 acc[2] = {};
        #pragma unroll
        for (int ks = 0; ks < 8; ++ks) {
            bf16x8 af[2];
            #pragma unroll
            for (int fr = 0; fr < 2; ++fr)
                af[fr] = lda_frag(bufA, 32, fr * 16 + m, ks * 4 + g);
            bf16x8 bf = ldb_frag(v2w, w * 16 + m, 256, ks * 4 + g);
            #pragma unroll
            for (int fr = 0; fr < 2; ++fr)
                acc[fr] = __builtin_amdgcn_mfma_f32_16x16x32_bf16(af[fr], bf, acc[fr], 0, 0, 0);
        }
        int col = w * 16 + m;
        float bv = v2_b[col];
        unsigned short* vb = (unsigned short*)bufB;  // bufB dead after v1
        #pragma unroll
        for (int fr = 0; fr < 2; ++fr) {
            #pragma unroll
            for (int i = 0; i < 4; ++i) {
                int rowl = fr * 16 + g * 4 + i;
                vb[rowl * 64 + col] = (unsigned short)f2bf(acc[fr][i] + bv);
            }
        }
    }
    __syncthreads();
    {   // 32x64 bf16 = 256 uint4: one per thread
        int row = tid >> 3, c = tid & 7;
        *(uint4*)(valb + (size_t)(r0 + row) * 64 + c * 8) = ((uint4*)bufB)[row * 8 + c];
    }
}

// ---------------------------------------------------------------------------
// vproj[r][na] = w2[na, 256+64*(r%16) .. +64] . value[r]   (value bf16, w2 f32)
__global__ __launch_bounds__(256)
void vproj_kernel(const unsigned short* __restrict__ value, const float* __restrict__ w2,
                  float* __restrict__ vproj)
{
    __shared__ float w2s[NA_][65];
    __shared__ float val_s[64][65];
    const int tid = threadIdx.x;
    const int j = blockIdx.x & 15;
    const int b0 = (blockIdx.x >> 4) * 64;

    for (int idx = tid; idx < NA_ * 64; idx += 256) {
        int na = idx >> 6, k = idx & 63;
        w2s[na][k] = w2[(size_t)na * 1280 + 256 + j * 64 + k];
    }
    for (int idx = tid; idx < 64 * 64; idx += 256) {
        int bl = idx >> 6, k = idx & 63;
        val_s[bl][k] = bf2f(value[((size_t)(b0 + bl) * 16 + j) * 64 + k]);
    }
    __syncthreads();

    for (int task = tid; task < 64 * NA_; task += 256) {
        int bl = task / NA_, na = task - bl * NA_;
        float acc = 0.f;
        #pragma unroll 16
        for (int k = 0; k < 64; ++k) acc = fmaf(val_s[bl][k], w2s[na][k], acc);
        vproj[((size_t)(b0 + bl) * 16 + j) * NA_ + na] = acc;
    }
}

// Per batch: cosine logits (16x16), softmax over j, zero diag, combine.
__global__ __launch_bounds__(256)
void attn_combine(const float* __restrict__ kh, const float* __restrict__ qh,
                  const float* __restrict__ vproj, const float* __restrict__ hl,
                  float* __restrict__ outv)
{
    __shared__ float kh_s[16][33], qh_s[16][33];
    __shared__ float al_s[16][16];
    __shared__ float vp_s[16][NA_];
    const int tid = threadIdx.x;
    const size_t rb = (size_t)blockIdx.x * 16;

    for (int idx = tid; idx < 512; idx += 256) {
        int r = idx >> 5, a = idx & 31;
        kh_s[r][a] = kh[rb * 32 + idx];
        qh_s[r][a] = qh[rb * 32 + idx];
    }
    for (int idx = tid; idx < 16 * NA_; idx += 256)
        vp_s[idx / NA_][idx % NA_] = vproj[rb * NA_ + idx];
    __syncthreads();

    {
        int i = tid >> 4, j = tid & 15;
        float l = 0.f;
        #pragma unroll
        for (int a = 0; a < 32; ++a) l = fmaf(kh_s[i][a], qh_s[j][a], l);
        float mx = l;
        #pragma unroll
        for (int mm = 8; mm >= 1; mm >>= 1) mx = fmaxf(mx, __shfl_xor(mx, mm));
        float e = __expf(l - mx);
        float s = e;
        #pragma unroll
        for (int mm = 8; mm >= 1; mm >>= 1) s += __shfl_xor(s, mm);
        float a = e / s;
        if (i == j) a = 0.f;
        al_s[i][j] = a;
    }
    __syncthreads();

    for (int task = tid; task < 16 * NA_; task += 256) {
        int i = task / NA_, na = task - i * NA_;
        float acc = hl[(rb + i) * NA_ + na];
        #pragma unroll
        for (int j = 0; j < 16; ++j) acc = fmaf(al_s[i][j], vp_s[j][na], acc);
        outv[(rb + i) * NA_ + na] = acc;
    }
}

extern "C" void kernel_launch(void* const* d_in, const int* in_sizes, int n_in,
                              void* d_out, int out_size, void* d_ws, size_t ws_size,
                              hipStream_t stream)
{
    (void)in_sizes; (void)n_in; (void)out_size; (void)ws_size;
    const float* inputs  = (const float*)d_in[0];
    const float* hidden  = (const float*)d_in[1];
    const float* latent  = (const float*)d_in[2];
    const float* eps     = (const float*)d_in[3];
    const float* fc1_w   = (const float*)d_in[4];
    const float* fc1_b   = (const float*)d_in[5];
    const float* w_ih    = (const float*)d_in[6];
    const float* w_hh    = (const float*)d_in[7];
    const float* b_ih    = (const float*)d_in[8];
    const float* b_hh    = (const float*)d_in[9];
    const float* lse_w1  = (const float*)d_in[10];
    const float* lse_b1  = (const float*)d_in[11];
    const float* lse_w2  = (const float*)d_in[12];
    const float* lse_b2  = (const float*)d_in[13];
    const float* me_w1   = (const float*)d_in[14];
    const float* me_b1   = (const float*)d_in[15];
    const float* me_g    = (const float*)d_in[16];
    const float* me_beta = (const float*)d_in[17];
    const float* me_w2   = (const float*)d_in[18];
    const float* me_b2   = (const float*)d_in[19];
    const float* k_w     = (const float*)d_in[20];
    const float* k_b     = (const float*)d_in[21];
    const float* q_w     = (const float*)d_in[22];
    const float* q_b     = (const float*)d_in[23];
    const float* v_w1    = (const float*)d_in[24];
    const float* v_b1    = (const float*)d_in[25];
    const float* v_w2    = (const float*)d_in[26];
    const float* v_b2    = (const float*)d_in[27];
    const float* fc2_w   = (const float*)d_in[28];
    const float* fc2_b   = (const float*)d_in[29];

    const size_t R = R_;
    // Workspace layout: bf16 activations, bf16 weights, then f32 buffers.
    unsigned short* bws = (unsigned short*)d_ws;
    unsigned short* hb   = bws;               // R*128
    unsigned short* leb  = hb + R * 128;      // R*128
    unsigned short* t1b  = leb + R * 128;     // R*256
    unsigned short* valb = t1b + R * 256;     // R*64
    unsigned short* wb   = valb + R * 64;     // 347648 (bf16 weights)
    float* fws  = (float*)(wb + woff::total);
    float* khf  = fws;                 // R*32
    float* qhf  = khf + R * 32;        // R*32
    float* hlf  = qhf + R * 32;        // R*30
    float* vpf  = hlf + R * 30;        // R*30
    float* psum = vpf + R * 30;        // NBLK_*256
    float* psq  = psum + (size_t)NBLK_ * 256;
    float* scale = psq + (size_t)NBLK_ * 256;
    float* shift = scale + 256;

    dim3 blk(256);
    dim3 g1024(NBLK_);

    // 0) weights -> bf16 (once per call; cheap)
    wcvt_kernel<<<dim3((woff::total + 255) / 256), blk, 0, stream>>>(
        fc1_w, w_ih, w_hh, lse_w1, lse_w2, me_w1, me_w2, k_w, q_w, v_w1, v_w2, fc2_w, wb);

    // 1) merged stage1 (64-row tiles, 512 threads, (512,4): 128-reg cap, no spill):
    //    fc1+GRU (blocks 0..511), lse1+lse2 (blocks 512..1023)
    stage1<<<dim3(2 * NB64_), dim3(512), 0, stream>>>(
        inputs, hidden, wb + woff::fc1, fc1_b, wb + woff::ih, wb + woff::hh,
        b_ih, b_hh, hb,
        latent, wb + woff::l1, lse_b1, wb + woff::l2, lse_b2, leb);
    // 2) t1 = me1(cat(h,le)) -> bf16 + BN partial stats + hl projection
    me1_stats<<<g1024, blk, 0, stream>>>(hb, leb, wb + woff::m1, me_b1,
                                         wb + woff::f2, fc2_b, t1b, psum, psq, hlf);
    // 2b) BN finalize (parallel: one block per feature)
    bn_final_kernel<<<dim3(256), blk, 0, stream>>>(psum, psq, me_g, me_beta, scale, shift);
    // 3) fused me2(BN(t1)) -> pm [LDS] -> kq_norm + v1 + v2 -> kh/qh/value
    me2kqv<<<g1024, blk, 0, stream>>>(t1b, scale, shift, wb + woff::m2, me_b2, eps,
                                      hb, wb + woff::kw, k_b, wb + woff::qw, q_b,
                                      wb + woff::v1, v_b1, wb + woff::v2, v_b2,
                                      khf, qhf, valb);
    // 4) vproj = per-agent fc2_w slice . value
    vproj_kernel<<<dim3(16 * (BSB_ / 64)), blk, 0, stream>>>(valb, fc2_w, vpf);
    // 5) softmax + combine -> out
    attn_combine<<<dim3(BSB_), blk, 0, stream>>>(khf, qhf, vpf, hlf, (float*)d_out);
}

// Round 17
// 110.044 us; speedup vs baseline: 1.3960x; 1.1402x over previous
//
#include <hip/hip_runtime.h>
#include <math.h>

// Problem constants (fixed instance)
namespace {
constexpr int R_ = 32768;     // BS*N rows
constexpr int N_ = 16;
constexpr int NA_ = 30;
constexpr int BSB_ = R_ / N_; // 2048 batches
constexpr int NB64_ = R_ / 64; // 512 row-blocks (64 rows each)
}

typedef __bf16 bf16x8 __attribute__((ext_vector_type(8)));
typedef float f32x4 __attribute__((ext_vector_type(4)));

__device__ inline unsigned int f2bf(float f) {
    unsigned int u = __float_as_uint(f);
    return (u + 0x7fffu + ((u >> 16) & 1u)) >> 16;  // RTN-even
}
__device__ inline float bf2f(unsigned int us) {
    return __uint_as_float(us << 16);
}
__device__ inline unsigned int pack2(float a, float b) {
    return f2bf(a) | (f2bf(b) << 16);
}
__device__ inline uint4 pack8(float4 f0, float4 f1) {
    uint4 u;
    u.x = pack2(f0.x, f0.y); u.y = pack2(f0.z, f0.w);
    u.z = pack2(f1.x, f1.y); u.w = pack2(f1.z, f1.w);
    return u;
}
// Fast transcendentals (v_exp/v_rcp); rel err ~2^-21 << bf16 rounding 2^-9.
__device__ inline float fsig(float x)  { return __builtin_amdgcn_rcpf(1.f + __expf(-x)); }
__device__ inline float ftanh(float x) { return 1.f - 2.f * __builtin_amdgcn_rcpf(__expf(2.f * x) + 1.f); }

// A fragment from swizzled LDS tile (KC = 16B-chunks per row)
__device__ __forceinline__ bf16x8 lda_frag(const uint4* At, int KC, int row, int c) {
    return __builtin_bit_cast(bf16x8, At[(row * KC + c) ^ (row & 7)]);
}
// B fragment direct from global bf16 weights
__device__ __forceinline__ bf16x8 ldb_frag(const unsigned short* W, int row, int rstride, int c) {
    return __builtin_bit_cast(bf16x8, *(const uint4*)(W + (size_t)row * rstride + (size_t)c * 8));
}

// ---------------------------------------------------------------------------
// One-shot weight conversion f32 -> bf16 into workspace (concatenated).
namespace woff {
constexpr unsigned fc1 = 0;
constexpr unsigned ih  = 16384;
constexpr unsigned hh  = 65536;
constexpr unsigned l1  = 114688;
constexpr unsigned l2  = 122880;
constexpr unsigned m1  = 139264;
constexpr unsigned m2  = 204800;
constexpr unsigned kw  = 237568;
constexpr unsigned qw  = 241664;
constexpr unsigned v1  = 243712;
constexpr unsigned v2  = 292864;
constexpr unsigned f2  = 309248;
constexpr unsigned total = 347648;
}

__global__ __launch_bounds__(256)
void wcvt_kernel(const float* __restrict__ fc1_w, const float* __restrict__ w_ih,
                 const float* __restrict__ w_hh, const float* __restrict__ lse_w1,
                 const float* __restrict__ lse_w2, const float* __restrict__ me_w1,
                 const float* __restrict__ me_w2, const float* __restrict__ k_w,
                 const float* __restrict__ q_w, const float* __restrict__ v_w1,
                 const float* __restrict__ v_w2, const float* __restrict__ fc2_w,
                 unsigned short* __restrict__ dst)
{
    unsigned i = blockIdx.x * 256 + threadIdx.x;
    if (i >= woff::total) return;
    const float* src; unsigned base;
    if      (i < woff::ih) { src = fc1_w;  base = woff::fc1; }
    else if (i < woff::hh) { src = w_ih;   base = woff::ih; }
    else if (i < woff::l1) { src = w_hh;   base = woff::hh; }
    else if (i < woff::l2) { src = lse_w1; base = woff::l1; }
    else if (i < woff::m1) { src = lse_w2; base = woff::l2; }
    else if (i < woff::m2) { src = me_w1;  base = woff::m1; }
    else if (i < woff::kw) { src = me_w2;  base = woff::m2; }
    else if (i < woff::qw) { src = k_w;    base = woff::kw; }
    else if (i < woff::v1) { src = q_w;    base = woff::qw; }
    else if (i < woff::v2) { src = v_w1;   base = woff::v1; }
    else if (i < woff::f2) { src = v_w2;   base = woff::v2; }
    else                   { src = fc2_w;  base = woff::f2; }
    dst[i] = (unsigned short)f2bf(src[i - base]);
}

// ---------------------------------------------------------------------------
// Merged stage 1, 64-row tiles, 512 threads / 8 waves, wave w: 16-col strip
// with 4 row-fragments (B-frag reuse x4). (512,4): no spill (r16 verified).
__global__ __launch_bounds__(512, 4)
void stage1(const float* __restrict__ inputs, const float* __restrict__ hidden,
            const unsigned short* __restrict__ fc1w, const float* __restrict__ fc1_b,
            const unsigned short* __restrict__ wih, const unsigned short* __restrict__ whh,
            const float* __restrict__ b_ih, const float* __restrict__ b_hh,
            unsigned short* __restrict__ hb,
            const float* __restrict__ latent,
            const unsigned short* __restrict__ w1b, const float* __restrict__ b1,
            const unsigned short* __restrict__ w2b, const float* __restrict__ b2,
            unsigned short* __restrict__ leb)
{
    __shared__ uint4 shbuf[64 * 48];   // 48 KB, unioned between both paths
    const int tid = threadIdx.x;
    const int lane = tid & 63, w = tid >> 6;      // w: 0..7
    const int m = lane & 15, g = lane >> 4;

    if (blockIdx.x < (unsigned)NB64_) {
        // ================= fc1 + GRU =================
        uint4* Ain   = shbuf;            // 64x16: inputs bf16
        uint4* Atile = shbuf + 64 * 16;  // 64x32: [x | hidden] bf16
        const int r0 = blockIdx.x * 64;

        for (int idx = tid; idx < 64 * 16; idx += 512) {
            int row = idx >> 4, c = idx & 15;
            const float4* p = (const float4*)(inputs + (size_t)(r0 + row) * 128 + c * 8);
            Ain[(row * 16 + c) ^ (row & 7)] = pack8(p[0], p[1]);
            const float4* ph = (const float4*)(hidden + (size_t)(r0 + row) * 128 + c * 8);
            Atile[(row * 32 + (16 + c)) ^ (row & 7)] = pack8(ph[0], ph[1]);
        }
        __syncthreads();

        // ---- phase 1: x = relu(fc1); wave w: cols w*16..w*16+15, 64 rows ----
        {
            f32x4 acc[4] = {};
            #pragma unroll
            for (int ks = 0; ks < 4; ++ks) {
                bf16x8 bf = ldb_frag(fc1w, w * 16 + m, 128, ks * 4 + g);
                #pragma unroll
                for (int fr = 0; fr < 4; ++fr) {
                    bf16x8 af = lda_frag(Ain, 16, fr * 16 + m, ks * 4 + g);
                    acc[fr] = __builtin_amdgcn_mfma_f32_16x16x32_bf16(af, bf, acc[fr], 0, 0, 0);
                }
            }
            int col = w * 16 + m;
            float bv = fc1_b[col];
            int c = col >> 3, el = col & 7;
            #pragma unroll
            for (int fr = 0; fr < 4; ++fr) {
                #pragma unroll
                for (int i = 0; i < 4; ++i) {
                    int row = fr * 16 + g * 4 + i;
                    float v = acc[fr][i] + bv;
                    v = v > 0.f ? v : 0.f;
                    ((unsigned short*)Atile)[((row * 32 + c) ^ (row & 7)) * 8 + el] =
                        (unsigned short)f2bf(v);
                }
            }
        }
        __syncthreads();

        // ---- phase 2: GRU; wave w: gate cols w*16..w*16+15, 64 rows ----
        {
            f32x4 rr[4] = {}, zz[4] = {}, ni[4] = {}, nh[4] = {};
            const int ro = w * 16 + m;
            #pragma unroll
            for (int ks = 0; ks < 4; ++ks) {  // x part: wih
                bf16x8 brr = ldb_frag(wih, ro, 128, ks * 4 + g);
                bf16x8 bzz = ldb_frag(wih, 128 + ro, 128, ks * 4 + g);
                bf16x8 bnn = ldb_frag(wih, 256 + ro, 128, ks * 4 + g);
                #pragma unroll
                for (int fr = 0; fr < 4; ++fr) {
                    bf16x8 af = lda_frag(Atile, 32, fr * 16 + m, ks * 4 + g);
                    rr[fr] = __builtin_amdgcn_mfma_f32_16x16x32_bf16(af, brr, rr[fr], 0, 0, 0);
                    zz[fr] = __builtin_amdgcn_mfma_f32_16x16x32_bf16(af, bzz, zz[fr], 0, 0, 0);
                    ni[fr] = __builtin_amdgcn_mfma_f32_16x16x32_bf16(af, bnn, ni[fr], 0, 0, 0);
                }
            }
            #pragma unroll
            for (int ks = 0; ks < 4; ++ks) {  // hidden part: whh
                bf16x8 brr = ldb_frag(whh, ro, 128, ks * 4 + g);
                bf16x8 bzz = ldb_frag(whh, 128 + ro, 128, ks * 4 + g);
                bf16x8 bnn = ldb_frag(whh, 256 + ro, 128, ks * 4 + g);
                #pragma unroll
                for (int fr = 0; fr < 4; ++fr) {
                    bf16x8 af = lda_frag(Atile, 32, fr * 16 + m, 16 + ks * 4 + g);
                    rr[fr] = __builtin_amdgcn_mfma_f32_16x16x32_bf16(af, brr, rr[fr], 0, 0, 0);
                    zz[fr] = __builtin_amdgcn_mfma_f32_16x16x32_bf16(af, bzz, zz[fr], 0, 0, 0);
                    nh[fr] = __builtin_amdgcn_mfma_f32_16x16x32_bf16(af, bnn, nh[fr], 0, 0, 0);
                }
            }
            {
                int c = ro;   // 0..127
                float brz = b_ih[c] + b_hh[c];
                float bzz2 = b_ih[128 + c] + b_hh[128 + c];
                float bin = b_ih[256 + c], bhn = b_hh[256 + c];
                int hc = 16 + (c >> 3), hel = c & 7;  // hidden chunk in Atile
                #pragma unroll
                for (int fr = 0; fr < 4; ++fr) {
                    #pragma unroll
                    for (int i = 0; i < 4; ++i) {
                        int row = fr * 16 + g * 4 + i;
                        float rv = fsig(rr[fr][i] + brz);
                        float zv = fsig(zz[fr][i] + bzz2);
                        float ng = ftanh(ni[fr][i] + bin + rv * (nh[fr][i] + bhn));
                        float hp = bf2f(((unsigned short*)Atile)[((row * 32 + hc) ^ (row & 7)) * 8 + hel]);
                        float hv = ng + zv * (hp - ng);
                        hb[(size_t)(r0 + row) * 128 + c] = (unsigned short)f2bf(hv);
                    }
                }
            }
        }
    } else {
        // ================= lse1 + lse2 =================
        uint4* Alat = shbuf;            // 64x8
        uint4* Alt  = shbuf + 64 * 8;   // 64x16
        const int r0 = (blockIdx.x - NB64_) * 64;

        {   // 512 items, one per thread
            int row = tid >> 3, c = tid & 7;
            const float4* p = (const float4*)(latent + (size_t)(r0 + row) * 64 + c * 8);
            Alat[(row * 8 + c) ^ (row & 7)] = pack8(p[0], p[1]);
        }
        __syncthreads();

        // lse1: K=64, O=128; wave w: cols w*16 -> Alt
        {
            f32x4 acc[4] = {};
            #pragma unroll
            for (int ks = 0; ks < 2; ++ks) {
                bf16x8 bf = ldb_frag(w1b, w * 16 + m, 64, ks * 4 + g);
                #pragma unroll
                for (int fr = 0; fr < 4; ++fr) {
                    bf16x8 af = lda_frag(Alat, 8, fr * 16 + m, ks * 4 + g);
                    acc[fr] = __builtin_amdgcn_mfma_f32_16x16x32_bf16(af, bf, acc[fr], 0, 0, 0);
                }
            }
            int col = w * 16 + m;
            float bv = b1[col];
            int c = col >> 3, el = col & 7;
            #pragma unroll
            for (int fr = 0; fr < 4; ++fr) {
                #pragma unroll
                for (int i = 0; i < 4; ++i) {
                    int row = fr * 16 + g * 4 + i;
                    float v = acc[fr][i] + bv;
                    v = v > 0.f ? v : 0.f;
                    ((unsigned short*)Alt)[((row * 16 + c) ^ (row & 7)) * 8 + el] =
                        (unsigned short)f2bf(v);
                }
            }
        }
        __syncthreads();

        // lse2: K=128, O=128 -> leb
        {
            f32x4 acc[4] = {};
            #pragma unroll
            for (int ks = 0; ks < 4; ++ks) {
                bf16x8 bf = ldb_frag(w2b, w * 16 + m, 128, ks * 4 + g);
                #pragma unroll
                for (int fr = 0; fr < 4; ++fr) {
                    bf16x8 af = lda_frag(Alt, 16, fr * 16 + m, ks * 4 + g);
                    acc[fr] = __builtin_amdgcn_mfma_f32_16x16x32_bf16(af, bf, acc[fr], 0, 0, 0);
                }
            }
            int col = w * 16 + m;
            float bv = b2[col];
            #pragma unroll
            for (int fr = 0; fr < 4; ++fr) {
                #pragma unroll
                for (int i = 0; i < 4; ++i) {
                    int rowl = fr * 16 + g * 4 + i;
                    float v = acc[fr][i] + bv;
                    leb[(size_t)(r0 + rowl) * 128 + col] = (unsigned short)f2bf(v);
                }
            }
        }
    }
}

// ---------------------------------------------------------------------------
// me1 GEMM (K=256, O=256) + BN partials + fused hl, 64-row blocks, 512 thr.
// 8 waves x 32-col strips cover O=256 in one pass; 4 row-frags (B-reuse x4).
__global__ __launch_bounds__(512, 4)
void me1_stats(const unsigned short* __restrict__ hb, const unsigned short* __restrict__ leb,
               const unsigned short* __restrict__ W, const float* __restrict__ bias,
               const unsigned short* __restrict__ f2w, const float* __restrict__ fc2_b,
               unsigned short* __restrict__ t1,
               float* __restrict__ psum, float* __restrict__ psq,
               float* __restrict__ hl)
{
    __shared__ uint4 Atile[64 * 32];   // 32 KB: [h | le]
    __shared__ uint4 T1b[64 * 32];     // 32 KB: t1 bounce (linear 64x256 bf16)
    const int tid = threadIdx.x;
    const int r0 = blockIdx.x * 64;

    for (int idx = tid; idx < 64 * 16; idx += 512) {
        int row = idx >> 4, c = idx & 15;
        Atile[(row * 32 + c) ^ (row & 7)] =
            *(const uint4*)(hb + (size_t)(r0 + row) * 128 + c * 8);
        Atile[(row * 32 + (16 + c)) ^ (row & 7)] =
            *(const uint4*)(leb + (size_t)(r0 + row) * 128 + c * 8);
    }
    __syncthreads();

    const int lane = tid & 63, w = tid >> 6;
    const int m = lane & 15, g = lane >> 4;
    unsigned short* t1s = (unsigned short*)T1b;

    {
        const int o0 = w * 32;
        f32x4 acc[4][2] = {};
        #pragma unroll
        for (int ks = 0; ks < 8; ++ks) {
            bf16x8 bf[2];
            #pragma unroll
            for (int fc = 0; fc < 2; ++fc)
                bf[fc] = ldb_frag(W, o0 + fc * 16 + m, 256, ks * 4 + g);
            #pragma unroll
            for (int fr = 0; fr < 4; ++fr) {
                bf16x8 af = lda_frag(Atile, 32, fr * 16 + m, ks * 4 + g);
                #pragma unroll
                for (int fc = 0; fc < 2; ++fc)
                    acc[fr][fc] = __builtin_amdgcn_mfma_f32_16x16x32_bf16(
                        af, bf[fc], acc[fr][fc], 0, 0, 0);
            }
        }
        #pragma unroll
        for (int fc = 0; fc < 2; ++fc) {
            int col = o0 + fc * 16 + m;
            float bv = bias[col];
            float s = 0.f, q = 0.f;
            #pragma unroll
            for (int fr = 0; fr < 4; ++fr) {
                #pragma unroll
                for (int i = 0; i < 4; ++i) {
                    int rowl = fr * 16 + g * 4 + i;
                    float v = acc[fr][fc][i] + bv;
                    t1s[rowl * 256 + col] = (unsigned short)f2bf(v);
                    s += v; q += v * v;
                }
            }
            s += __shfl_xor(s, 16); s += __shfl_xor(s, 32);  // over g: all 64 rows
            q += __shfl_xor(q, 16); q += __shfl_xor(q, 32);
            if (lane < 16) {
                psum[(size_t)blockIdx.x * 256 + col] = s;
                psq[(size_t)blockIdx.x * 256 + col] = q;
            }
        }
    }
    __syncthreads();
    for (int idx = tid; idx < 64 * 32; idx += 512) {  // coalesced t1 store
        int row = idx >> 5, c = idx & 31;
        *(uint4*)(t1 + (size_t)(r0 + row) * 256 + c * 8) = T1b[row * 32 + c];
    }

    // ---- fused hl: waves 0-3, rows w*16..w*16+15, cols 0..29 ----
    if (w < 4) {
        f32x4 acc[2] = {};
        #pragma unroll
        for (int ks = 0; ks < 8; ++ks) {
            bf16x8 af = lda_frag(Atile, 32, w * 16 + m, ks * 4 + g);
            bf16x8 bf[2];
            #pragma unroll
            for (int fc = 0; fc < 2; ++fc) {
                int col = fc * 16 + m;
                bf[fc] = (col < NA_) ? ldb_frag(f2w, col, 1280, ks * 4 + g) : bf16x8{};
            }
            #pragma unroll
            for (int fc = 0; fc < 2; ++fc)
                acc[fc] = __builtin_amdgcn_mfma_f32_16x16x32_bf16(af, bf[fc], acc[fc], 0, 0, 0);
        }
        #pragma unroll
        for (int fc = 0; fc < 2; ++fc) {
            int col = fc * 16 + m;
            if (col < NA_) {
                float bv = fc2_b[col];
                #pragma unroll
                for (int i = 0; i < 4; ++i) {
                    int row = r0 + w * 16 + g * 4 + i;
                    hl[(size_t)row * NA_ + col] = acc[fc][i] + bv;
                }
            }
        }
    }
}

// ---------------------------------------------------------------------------
// Parallel BN finalize: one block per feature; threads stride over NB64_.
__global__ __launch_bounds__(256)
void bn_final_kernel(const float* __restrict__ psum, const float* __restrict__ psq,
                     const float* __restrict__ g, const float* __restrict__ beta,
                     float* __restrict__ scale, float* __restrict__ shift)
{
    __shared__ float redS[4], redQ[4];
    const int f = blockIdx.x;
    const int tid = threadIdx.x;
    float s = 0.f, q = 0.f;
    for (int b = tid; b < NB64_; b += 256) {
        s += psum[(size_t)b * 256 + f];
        q += psq[(size_t)b * 256 + f];
    }
    #pragma unroll
    for (int off = 32; off >= 1; off >>= 1) {
        s += __shfl_down(s, off);
        q += __shfl_down(q, off);
    }
    if ((tid & 63) == 0) { redS[tid >> 6] = s; redQ[tid >> 6] = q; }
    __syncthreads();
    if (tid == 0) {
        s = redS[0] + redS[1] + redS[2] + redS[3];
        q = redQ[0] + redQ[1] + redQ[2] + redQ[3];
        float mean = s / (float)R_;
        float var = q / (float)R_ - mean * mean;
        float istd = rsqrtf(var + 1e-5f);
        float sc = g[f] * istd;
        scale[f] = sc;
        shift[f] = beta[f] - mean * sc;
    }
}

// ---------------------------------------------------------------------------
// Fused me2 + kq_norm + v1 + v2, 64-row blocks, 512 threads / 8 waves.
// me2 O=128 maps onto 8 waves x 16 cols (w<4 mean, w>=4 std); mean published
// via f32 LDS scratch (dead t1 space) -> identical rounding to 32-row version.
__global__ __launch_bounds__(512, 4)
void me2kqv(const unsigned short* __restrict__ t1,
            const float* __restrict__ scale, const float* __restrict__ shift,
            const unsigned short* __restrict__ W2, const float* __restrict__ me2_b,
            const float* __restrict__ eps,
            const unsigned short* __restrict__ hb,
            const unsigned short* __restrict__ kwb, const float* __restrict__ k_b,
            const unsigned short* __restrict__ qwb, const float* __restrict__ q_b,
            const unsigned short* __restrict__ v1w, const float* __restrict__ v1_b,
            const unsigned short* __restrict__ v2w, const float* __restrict__ v2_b,
            float* __restrict__ kh, float* __restrict__ qh,
            unsigned short* __restrict__ valb)
{
    __shared__ uint4 bufA[64 * 32];   // 32 KB: t1(BN) -> mean scratch -> A3 (t3)
    __shared__ uint4 bufB[64 * 24];   // 24 KB: [h 0..15 | pm 16..23] -> val bounce
    __shared__ float sc_s[256], sh_s[256];
    const int tid = threadIdx.x;
    const int r0 = blockIdx.x * 64;
    const int lane = tid & 63, w = tid >> 6;   // w: 0..7
    const int m = lane & 15, g = lane >> 4;

    if (tid < 256) { sc_s[tid] = scale[tid]; sh_s[tid] = shift[tid]; }
    for (int idx = tid; idx < 64 * 16; idx += 512) {
        int row = idx >> 4, c = idx & 15;
        bufB[(row * 24 + c) ^ (row & 7)] =
            *(const uint4*)(hb + (size_t)(r0 + row) * 128 + c * 8);
    }
    __syncthreads();

    // stage t1 with BN(scale/shift)+lrelu -> bufA (swizzled)
    for (int idx = tid; idx < 64 * 32; idx += 512) {
        int row = idx >> 5, c = idx & 31;
        uint4 u = *(const uint4*)(t1 + (size_t)(r0 + row) * 256 + c * 8);
        unsigned int vv[4] = {u.x, u.y, u.z, u.w};
        float f[8];
        #pragma unroll
        for (int q2 = 0; q2 < 4; ++q2) {
            f[2 * q2]     = __uint_as_float((vv[q2] & 0xffffu) << 16);
            f[2 * q2 + 1] = __uint_as_float(vv[q2] & 0xffff0000u);
        }
        int k = c * 8;
        #pragma unroll
        for (int j = 0; j < 8; ++j) {
            float v = f[j] * sc_s[k + j] + sh_s[k + j];
            f[j] = v > 0.f ? v : 0.01f * v;
        }
        uint4 r;
        r.x = pack2(f[0], f[1]); r.y = pack2(f[2], f[3]);
        r.z = pack2(f[4], f[5]); r.w = pack2(f[6], f[7]);
        bufA[(row * 32 + c) ^ (row & 7)] = r;
    }
    __syncthreads();

    // ---- me2 GEMM: wave w owns output col w*16+m (0..127); 4 row frags ----
    {
        const int colm = w * 16 + m;       // 0..63 mean, 64..127 std
        f32x4 acc[4] = {};
        #pragma unroll
        for (int ks = 0; ks < 8; ++ks) {
            bf16x8 bf = ldb_frag(W2, colm, 256, ks * 4 + g);
            #pragma unroll
            for (int fr = 0; fr < 4; ++fr) {
                bf16x8 af = lda_frag(bufA, 32, fr * 16 + m, ks * 4 + g);
                acc[fr] = __builtin_amdgcn_mfma_f32_16x16x32_bf16(af, bf, acc[fr], 0, 0, 0);
            }
        }
        float bv = me2_b[colm];
        __syncthreads();   // all bufA (t1) reads done; reuse as f32 mean scratch
        float* meanS = (float*)bufA;       // [64][64] f32 (16 KB of bufA)
        if (w < 4) {       // mean cols: clip(lrelu(.)) -> scratch
            #pragma unroll
            for (int fr = 0; fr < 4; ++fr) {
                #pragma unroll
                for (int i = 0; i < 4; ++i) {
                    int row = fr * 16 + g * 4 + i;
                    float vm = acc[fr][i] + bv;
                    vm = vm > 0.f ? vm : 0.01f * vm;
                    vm = fminf(fmaxf(vm, -1.f), 1.f);
                    meanS[row * 64 + colm] = vm;
                }
            }
        }
        __syncthreads();
        if (w >= 4) {      // std cols: combine with mean + eps -> pm in bufB
            int cp = colm - 64;            // 0..63
            int hc = 16 + (cp >> 3), hel = cp & 7;
            #pragma unroll
            for (int fr = 0; fr < 4; ++fr) {
                #pragma unroll
                for (int i = 0; i < 4; ++i) {
                    int row = fr * 16 + g * 4 + i;
                    float vs = acc[fr][i] + bv;
                    vs = vs > 0.f ? vs : 0.01f * vs;
                    vs = fminf(fmaxf(vs, 0.5f), 1.f);
                    float e = eps[(size_t)(r0 + row) * 64 + cp];
                    float vm = meanS[row * 64 + cp];
                    ((unsigned short*)bufB)[((row * 24 + hc) ^ (row & 7)) * 8 + hel] =
                        (unsigned short)f2bf(vm + vs * e);
                }
            }
        }
    }
    __syncthreads();   // pm visible in bufB; meanS consumed (bufA free for A3)

    // ---- kq-norm: waves 0-3. w0: kh rows 0-31, w1: kh rows 32-63,
    //      w2: qh rows 0-31, w3: qh rows 32-63.
    if (w < 4) {
        const bool isq = (w >= 2);
        const int rbase = (w & 1) * 32;
        f32x4 acc[2][2] = {};
        const int nks = isq ? 2 : 4;
        for (int ks = 0; ks < nks; ++ks) {
            bf16x8 af[2], bf[2];
            #pragma unroll
            for (int fr = 0; fr < 2; ++fr)
                af[fr] = lda_frag(bufB, 24, rbase + fr * 16 + m, (isq ? 16 : 0) + ks * 4 + g);
            #pragma unroll
            for (int fc = 0; fc < 2; ++fc)
                bf[fc] = isq ? ldb_frag(qwb, fc * 16 + m, 64, ks * 4 + g)
                             : ldb_frag(kwb, fc * 16 + m, 128, ks * 4 + g);
            #pragma unroll
            for (int fr = 0; fr < 2; ++fr)
                #pragma unroll
                for (int fc = 0; fc < 2; ++fc)
                    acc[fr][fc] = __builtin_amdgcn_mfma_f32_16x16x32_bf16(
                        af[fr], bf[fc], acc[fr][fc], 0, 0, 0);
        }
        const float* bias = isq ? q_b : k_b;
        float b0 = bias[m], b1 = bias[16 + m];
        float* outp = isq ? qh : kh;
        #pragma unroll
        for (int fr = 0; fr < 2; ++fr) {
            #pragma unroll
            for (int i = 0; i < 4; ++i) {
                float v0 = acc[fr][0][i] + b0;
                float v1 = acc[fr][1][i] + b1;
                float ss = v0 * v0 + v1 * v1;
                ss += __shfl_xor(ss, 1); ss += __shfl_xor(ss, 2);
                ss += __shfl_xor(ss, 4); ss += __shfl_xor(ss, 8);
                float inv = 1.f / fmaxf(sqrtf(ss), 1e-8f);
                int row = r0 + rbase + fr * 16 + g * 4 + i;
                outp[(size_t)row * 32 + m] = v0 * inv;
                outp[(size_t)row * 32 + 16 + m] = v1 * inv;
            }
        }
    }

    // ---- v1 (K=192, O=256): 8 waves x 32 cols, 4 row frags -> bufA as A3 ----
    {
        const int o0 = w * 32;
        f32x4 acc[4][2] = {};
        #pragma unroll
        for (int ks = 0; ks < 6; ++ks) {
            bf16x8 bf[2];
            #pragma unroll
            for (int fc = 0; fc < 2; ++fc)
                bf[fc] = ldb_frag(v1w, o0 + fc * 16 + m, 192, ks * 4 + g);
            #pragma unroll
            for (int fr = 0; fr < 4; ++fr) {
                bf16x8 af = lda_frag(bufB, 24, fr * 16 + m, ks * 4 + g);
                #pragma unroll
                for (int fc = 0; fc < 2; ++fc)
                    acc[fr][fc] = __builtin_amdgcn_mfma_f32_16x16x32_bf16(
                        af, bf[fc], acc[fr][fc], 0, 0, 0);
            }
        }
        #pragma unroll
        for (int fc = 0; fc < 2; ++fc) {
            int col = o0 + fc * 16 + m;
            float bv = v1_b[col];
            int c = col >> 3, el = col & 7;
            #pragma unroll
            for (int fr = 0; fr < 4; ++fr) {
                #pragma unroll
                for (int i = 0; i < 4; ++i) {
                    int row = fr * 16 + g * 4 + i;
                    float v = acc[fr][fc][i] + bv;
                    v = v > 0.f ? v : 0.01f * v;
                    ((unsigned short*)bufA)[((row * 32 + c) ^ (row & 7)) * 8 + el] =
                        (unsigned short)f2bf(v);
                }
            }
        }
    }
    __syncthreads();

    // ---- v2 (K=256, O=64): wave w: col (w&3)*16+m, rows (w>>2)*32.. ----
    {
        const int col = (w & 3) * 16 + m;
        const int rbase = (w >> 2) * 32;
        f32x4 acc[2] = {};
        #pragma unroll
        for (int ks = 0; ks < 8; ++ks) {
            bf16x8 bf = ldb_frag(v2w, col, 256, ks * 4 + g);
            #pragma unroll
            for (int fr = 0; fr < 2; ++fr) {
                bf16x8 af = lda_frag(bufA, 32, rbase + fr * 16 + m, ks * 4 + g);
                acc[fr] = __builtin_amdgcn_mfma_f32_16x16x32_bf16(af, bf, acc[fr], 0, 0, 0);
            }
        }
        float bv = v2_b[col];
        unsigned short* vb = (unsigned short*)bufB;  // bufB dead after v1
        #pragma unroll
        for (int fr = 0; fr < 2; ++fr) {
            #pragma unroll
            for (int i = 0; i < 4; ++i) {
                int rowl = rbase + fr * 16 + g * 4 + i;
                vb[rowl * 64 + col] = (unsigned short)f2bf(acc[fr][i] + bv);
            }
        }
    }
    __syncthreads();
    {   // 64x64 bf16 = 512 uint4: one per thread
        int row = tid >> 3, c = tid & 7;
        *(uint4*)(valb + (size_t)(r0 + row) * 64 + c * 8) = ((uint4*)bufB)[row * 8 + c];
    }
}

// ---------------------------------------------------------------------------
// vproj[r][na] = w2[na, 256+64*(r%16) .. +64] . value[r]   (value bf16, w2 f32)
__global__ __launch_bounds__(256)
void vproj_kernel(const unsigned short* __restrict__ value, const float* __restrict__ w2,
                  float* __restrict__ vproj)
{
    __shared__ float w2s[NA_][65];
    __shared__ float val_s[64][65];
    const int tid = threadIdx.x;
    const int j = blockIdx.x & 15;
    const int b0 = (blockIdx.x >> 4) * 64;

    for (int idx = tid; idx < NA_ * 64; idx += 256) {
        int na = idx >> 6, k = idx & 63;
        w2s[na][k] = w2[(size_t)na * 1280 + 256 + j * 64 + k];
    }
    for (int idx = tid; idx < 64 * 64; idx += 256) {
        int bl = idx >> 6, k = idx & 63;
        val_s[bl][k] = bf2f(value[((size_t)(b0 + bl) * 16 + j) * 64 + k]);
    }
    __syncthreads();

    for (int task = tid; task < 64 * NA_; task += 256) {
        int bl = task / NA_, na = task - bl * NA_;
        float acc = 0.f;
        #pragma unroll 16
        for (int k = 0; k < 64; ++k) acc = fmaf(val_s[bl][k], w2s[na][k], acc);
        vproj[((size_t)(b0 + bl) * 16 + j) * NA_ + na] = acc;
    }
}

// Per batch: cosine logits (16x16), softmax over j, zero diag, combine.
__global__ __launch_bounds__(256)
void attn_combine(const float* __restrict__ kh, const float* __restrict__ qh,
                  const float* __restrict__ vproj, const float* __restrict__ hl,
                  float* __restrict__ outv)
{
    __shared__ float kh_s[16][33], qh_s[16][33];
    __shared__ float al_s[16][16];
    __shared__ float vp_s[16][NA_];
    const int tid = threadIdx.x;
    const size_t rb = (size_t)blockIdx.x * 16;

    for (int idx = tid; idx < 512; idx += 256) {
        int r = idx >> 5, a = idx & 31;
        kh_s[r][a] = kh[rb * 32 + idx];
        qh_s[r][a] = qh[rb * 32 + idx];
    }
    for (int idx = tid; idx < 16 * NA_; idx += 256)
        vp_s[idx / NA_][idx % NA_] = vproj[rb * NA_ + idx];
    __syncthreads();

    {
        int i = tid >> 4, j = tid & 15;
        float l = 0.f;
        #pragma unroll
        for (int a = 0; a < 32; ++a) l = fmaf(kh_s[i][a], qh_s[j][a], l);
        float mx = l;
        #pragma unroll
        for (int mm = 8; mm >= 1; mm >>= 1) mx = fmaxf(mx, __shfl_xor(mx, mm));
        float e = __expf(l - mx);
        float s = e;
        #pragma unroll
        for (int mm = 8; mm >= 1; mm >>= 1) s += __shfl_xor(s, mm);
        float a = e / s;
        if (i == j) a = 0.f;
        al_s[i][j] = a;
    }
    __syncthreads();

    for (int task = tid; task < 16 * NA_; task += 256) {
        int i = task / NA_, na = task - i * NA_;
        float acc = hl[(rb + i) * NA_ + na];
        #pragma unroll
        for (int j = 0; j < 16; ++j) acc = fmaf(al_s[i][j], vp_s[j][na], acc);
        outv[(rb + i) * NA_ + na] = acc;
    }
}

extern "C" void kernel_launch(void* const* d_in, const int* in_sizes, int n_in,
                              void* d_out, int out_size, void* d_ws, size_t ws_size,
                              hipStream_t stream)
{
    (void)in_sizes; (void)n_in; (void)out_size; (void)ws_size;
    const float* inputs  = (const float*)d_in[0];
    const float* hidden  = (const float*)d_in[1];
    const float* latent  = (const float*)d_in[2];
    const float* eps     = (const float*)d_in[3];
    const float* fc1_w   = (const float*)d_in[4];
    const float* fc1_b   = (const float*)d_in[5];
    const float* w_ih    = (const float*)d_in[6];
    const float* w_hh    = (const float*)d_in[7];
    const float* b_ih    = (const float*)d_in[8];
    const float* b_hh    = (const float*)d_in[9];
    const float* lse_w1  = (const float*)d_in[10];
    const float* lse_b1  = (const float*)d_in[11];
    const float* lse_w2  = (const float*)d_in[12];
    const float* lse_b2  = (const float*)d_in[13];
    const float* me_w1   = (const float*)d_in[14];
    const float* me_b1   = (const float*)d_in[15];
    const float* me_g    = (const float*)d_in[16];
    const float* me_beta = (const float*)d_in[17];
    const float* me_w2   = (const float*)d_in[18];
    const float* me_b2   = (const float*)d_in[19];
    const float* k_w     = (const float*)d_in[20];
    const float* k_b     = (const float*)d_in[21];
    const float* q_w     = (const float*)d_in[22];
    const float* q_b     = (const float*)d_in[23];
    const float* v_w1    = (const float*)d_in[24];
    const float* v_b1    = (const float*)d_in[25];
    const float* v_w2    = (const float*)d_in[26];
    const float* v_b2    = (const float*)d_in[27];
    const float* fc2_w   = (const float*)d_in[28];
    const float* fc2_b   = (const float*)d_in[29];

    const size_t R = R_;
    // Workspace layout: bf16 activations, bf16 weights, then f32 buffers.
    unsigned short* bws = (unsigned short*)d_ws;
    unsigned short* hb   = bws;               // R*128
    unsigned short* leb  = hb + R * 128;      // R*128
    unsigned short* t1b  = leb + R * 128;     // R*256
    unsigned short* valb = t1b + R * 256;     // R*64
    unsigned short* wb   = valb + R * 64;     // 347648 (bf16 weights)
    float* fws  = (float*)(wb + woff::total);
    float* khf  = fws;                 // R*32
    float* qhf  = khf + R * 32;        // R*32
    float* hlf  = qhf + R * 32;        // R*30
    float* vpf  = hlf + R * 30;        // R*30
    float* psum = vpf + R * 30;        // NB64_*256
    float* psq  = psum + (size_t)NB64_ * 256;
    float* scale = psq + (size_t)NB64_ * 256;
    float* shift = scale + 256;

    dim3 blk(256);
    dim3 g512(NB64_);

    // 0) weights -> bf16 (once per call; cheap)
    wcvt_kernel<<<dim3((woff::total + 255) / 256), blk, 0, stream>>>(
        fc1_w, w_ih, w_hh, lse_w1, lse_w2, me_w1, me_w2, k_w, q_w, v_w1, v_w2, fc2_w, wb);

    // 1) merged stage1 (64-row, 512 thr): fc1+GRU (0..511), lse1+lse2 (512..1023)
    stage1<<<dim3(2 * NB64_), dim3(512), 0, stream>>>(
        inputs, hidden, wb + woff::fc1, fc1_b, wb + woff::ih, wb + woff::hh,
        b_ih, b_hh, hb,
        latent, wb + woff::l1, lse_b1, wb + woff::l2, lse_b2, leb);
    // 2) t1 = me1(cat(h,le)) + BN partials + hl (64-row, 512 thr)
    me1_stats<<<g512, dim3(512), 0, stream>>>(hb, leb, wb + woff::m1, me_b1,
                                              wb + woff::f2, fc2_b, t1b, psum, psq, hlf);
    // 2b) BN finalize (parallel: one block per feature)
    bn_final_kernel<<<dim3(256), blk, 0, stream>>>(psum, psq, me_g, me_beta, scale, shift);
    // 3) fused me2 -> pm [LDS] -> kq_norm + v1 + v2 (64-row, 512 thr)
    me2kqv<<<g512, dim3(512), 0, stream>>>(t1b, scale, shift, wb + woff::m2, me_b2, eps,
                                           hb, wb + woff::kw, k_b, wb + woff::qw, q_b,
                                           wb + woff::v1, v_b1, wb + woff::v2, v_b2,
                                           khf, qhf, valb);
    // 4) vproj = per-agent fc2_w slice . value
    vproj_kernel<<<dim3(16 * (BSB_ / 64)), blk, 0, stream>>>(valb, fc2_w, vpf);
    // 5) softmax + combine -> out
    attn_combine<<<dim3(BSB_), blk, 0, stream>>>(khf, qhf, vpf, hlf, (float*)d_out);
}